// Round 3
// baseline (5835.522 us; speedup 1.0000x reference)
//
#include <hip/hip_runtime.h>

// Problem constants (fixed by the reference)
#define HID 256
#define OUTC 128

// ---------------- degree / norm ----------------
__global__ void k_deg_init(float* deg, int n) {
    int i = blockIdx.x * blockDim.x + threadIdx.x;
    if (i < n) deg[i] = 1.0f;  // self-loop contributes 1
}

__global__ void k_deg_count(const int* __restrict__ dst, float* deg, int e) {
    int i = blockIdx.x * blockDim.x + threadIdx.x;
    if (i < e) atomicAdd(&deg[dst[i]], 1.0f);
}

__global__ void k_dinv(const float* __restrict__ deg, float* dinv, int n) {
    int i = blockIdx.x * blockDim.x + threadIdx.x;
    if (i < n) dinv[i] = rsqrtf(deg[i]);  // deg >= 1 always (self loops)
}

// ---------------- dense GEMM + fused self-loop/bias epilogue ----------------
// h[M,256] = (relu?)A[M,K] @ W[K,256]         (needed by edge gather)
// init[M,256] = b + dinv^2 * h                (scatter accumulation base)
// 32 rows per block staged in LDS; thread t owns output column t.
template <int K, bool RELU_IN>
__global__ __launch_bounds__(256) void k_gemm_fused(const float* __restrict__ A,
                                                    const float* __restrict__ W,
                                                    const float* __restrict__ bias,
                                                    const float* __restrict__ dinv,
                                                    float* __restrict__ h_out,
                                                    float* __restrict__ init_out, int M) {
    __shared__ float sA[32 * K];
    const int t = threadIdx.x;
    const int row0 = blockIdx.x * 32;

    for (int idx = t; idx < 32 * K; idx += 256) {
        float v = 0.0f;
        if (row0 + idx / K < M) v = A[(size_t)row0 * K + idx];
        sA[idx] = RELU_IN ? fmaxf(v, 0.0f) : v;
    }
    __syncthreads();

    float acc[32];
#pragma unroll
    for (int r = 0; r < 32; ++r) acc[r] = 0.0f;

    const int c = t;  // 0..255
    for (int k0 = 0; k0 < K; k0 += 4) {
        const float w0 = W[(k0 + 0) * HID + c];
        const float w1 = W[(k0 + 1) * HID + c];
        const float w2 = W[(k0 + 2) * HID + c];
        const float w3 = W[(k0 + 3) * HID + c];
#pragma unroll
        for (int r = 0; r < 32; ++r) {
            const float4 a = *(const float4*)&sA[r * K + k0];  // broadcast read (conflict-free)
            acc[r] += a.x * w0;
            acc[r] += a.y * w1;
            acc[r] += a.z * w2;
            acc[r] += a.w * w3;
        }
    }

    const float bc = bias[c];
    for (int r = 0; r < 32; ++r) {
        const int row = row0 + r;
        if (row < M) {
            const float dv = dinv[row];  // wave-uniform -> scalar load
            h_out[(size_t)row * HID + c] = acc[r];
            init_out[(size_t)row * HID + c] = bc + dv * dv * acc[r];
        }
    }
}

// ---------------- edge scatter: out[dst] += dinv[src]*dinv[dst] * h[src] ----------------
__global__ void k_scatter(const int* __restrict__ src, const int* __restrict__ dst,
                          const float* __restrict__ dinv, const float* __restrict__ h,
                          float* __restrict__ out, int e) {
    int tid = blockIdx.x * 256 + threadIdx.x;
    int ed = tid >> 6;
    int c4 = (tid & 63) << 2;
    if (ed >= e) return;
    const int s = src[ed];
    const int d = dst[ed];
    const float nrm = dinv[s] * dinv[d];
    const float4 hv = *(const float4*)(h + (size_t)s * HID + c4);
    float* o = out + (size_t)d * HID + c4;
    atomicAdd(o + 0, nrm * hv.x);
    atomicAdd(o + 1, nrm * hv.y);
    atomicAdd(o + 2, nrm * hv.z);
    atomicAdd(o + 3, nrm * hv.w);
}

// ---------------- mean pool over sorted batch (binary search, no atomics) ----------------
__global__ void k_pool(const float* __restrict__ h, const int* __restrict__ batch,
                       float* __restrict__ pooled, int n) {
    const int g = blockIdx.x;
    const int c = threadIdx.x;  // 256
    int a = 0, b = n;
    while (a < b) { int m = (a + b) >> 1; if (batch[m] < g) a = m + 1; else b = m; }
    const int start = a;
    b = n;
    while (a < b) { int m = (a + b) >> 1; if (batch[m] < g + 1) a = m + 1; else b = m; }
    const int end = a;
    float sum = 0.0f;
    for (int v = start; v < end; ++v) sum += fmaxf(h[(size_t)v * HID + c], 0.0f);
    const float cnt = (float)(end - start);
    pooled[g * HID + c] = sum / fmaxf(cnt, 1.0f);
}

// ---------------- final FC: out[G,128] = pooled[G,256] @ Wfc + bfc ----------------
__global__ void k_fc(const float* __restrict__ pooled, const float* __restrict__ W,
                     const float* __restrict__ b, float* __restrict__ out) {
    const int g = blockIdx.x;
    const int c = threadIdx.x;  // 128
    float acc = b[c];
    const float* p = pooled + g * HID;
    for (int k = 0; k < HID; ++k) acc += p[k] * W[k * OUTC + c];
    out[g * OUTC + c] = acc;
}

extern "C" void kernel_launch(void* const* d_in, const int* in_sizes, int n_in,
                              void* d_out, int out_size, void* d_ws, size_t ws_size,
                              hipStream_t stream) {
    const float* x   = (const float*)d_in[0];
    const int*   ei  = (const int*)d_in[1];
    const int*   bat = (const int*)d_in[2];
    const float* W1  = (const float*)d_in[3];
    const float* b1  = (const float*)d_in[4];
    const float* W2  = (const float*)d_in[5];
    const float* b2  = (const float*)d_in[6];
    const float* Wfc = (const float*)d_in[7];
    const float* bfc = (const float*)d_in[8];
    float* out = (float*)d_out;

    const int n = in_sizes[2];       // 50000 nodes (batch array length)
    const int e = in_sizes[1] / 2;   // 800000 edges
    const int* src = ei;
    const int* dst = ei + e;

    float* ws = (float*)d_ws;
    float* deg    = ws;                               // n
    float* dinv   = ws + n;                           // n
    float* bufA   = ws + 2 * (size_t)n;               // n*256 (h)
    float* bufB   = bufA + (size_t)n * HID;           // n*256 (aggregated)
    float* pooled = bufB + (size_t)n * HID;           // 128*256

    const int TB = 256;
    // degree + norm (shared by both layers)
    k_deg_init<<<(n + TB - 1) / TB, TB, 0, stream>>>(deg, n);
    k_deg_count<<<(e + TB - 1) / TB, TB, 0, stream>>>(dst, deg, e);
    k_dinv<<<(n + TB - 1) / TB, TB, 0, stream>>>(deg, dinv, n);

    const int gemm_blocks = (n + 31) / 32;
    const int edge_thr_blocks = (int)(((size_t)e * 64 + TB - 1) / TB);

    // Layer 1: h1 = x @ W1 (K=128); bufB = b1 + dinv^2*h1; scatter adds edges
    k_gemm_fused<128, false><<<gemm_blocks, TB, 0, stream>>>(x, W1, b1, dinv, bufA, bufB, n);
    k_scatter<<<edge_thr_blocks, TB, 0, stream>>>(src, dst, dinv, bufA, bufB, e);

    // Layer 2: h2 = relu(bufB) @ W2 (K=256); bufB' = b2 + dinv^2*h2; scatter
    k_gemm_fused<256, true><<<gemm_blocks, TB, 0, stream>>>(bufB, W2, b2, dinv, bufA, bufB, n);
    k_scatter<<<edge_thr_blocks, TB, 0, stream>>>(src, dst, dinv, bufA, bufB, e);

    // Pool (relu fused) + FC
    k_pool<<<128, 256, 0, stream>>>(bufB, bat, pooled, n);
    k_fc<<<128, 128, 0, stream>>>(pooled, Wfc, bfc, out);
}

// Round 4
// 887.270 us; speedup vs baseline: 6.5769x; 6.5769x over previous
//
#include <hip/hip_runtime.h>

// Problem constants (fixed by the reference)
#define HID 256
#define OUTC 128

// ---------------- CSR build: histogram / dinv / scan / fill ----------------
__global__ void k_hist(const int* __restrict__ dst, int* __restrict__ cnt, int e) {
    int i = blockIdx.x * blockDim.x + threadIdx.x;
    if (i < e) atomicAdd(&cnt[dst[i]], 1);
}

__global__ void k_dinv(const int* __restrict__ cnt, float* __restrict__ dinv, int n) {
    int i = blockIdx.x * blockDim.x + threadIdx.x;
    if (i < n) dinv[i] = rsqrtf((float)cnt[i] + 1.0f);  // +1 self loop
}

// Single-block exclusive scan of cnt -> row_ptr; resets cnt to 0 (reused as cursor).
__global__ __launch_bounds__(1024) void k_scan(int* __restrict__ cnt, int* __restrict__ row_ptr, int n) {
    __shared__ int sdata[1024];
    __shared__ int s_running;
    const int t = threadIdx.x;
    if (t == 0) s_running = 0;
    __syncthreads();
    for (int base = 0; base < n; base += 1024) {
        const int i = base + t;
        const int v = (i < n) ? cnt[i] : 0;
        sdata[t] = v;
        __syncthreads();
        for (int off = 1; off < 1024; off <<= 1) {
            int add = (t >= off) ? sdata[t - off] : 0;
            __syncthreads();
            sdata[t] += add;
            __syncthreads();
        }
        if (i < n) { row_ptr[i] = s_running + sdata[t] - v; cnt[i] = 0; }
        __syncthreads();
        if (t == 1023) s_running += sdata[1023];
        __syncthreads();
    }
    if (t == 0) row_ptr[n] = s_running;
}

__global__ void k_fill(const int* __restrict__ src, const int* __restrict__ dst,
                       const int* __restrict__ row_ptr, int* __restrict__ cursor,
                       int* __restrict__ csr_src, int e) {
    int i = blockIdx.x * blockDim.x + threadIdx.x;
    if (i < e) {
        const int d = dst[i];
        const int pos = row_ptr[d] + atomicAdd(&cursor[d], 1);
        csr_src[pos] = src[i];
    }
}

// ---------------- dense GEMM: h[M,256] = (relu?)A[M,K] @ W[K,256] ----------------
template <int K, bool RELU_IN>
__global__ __launch_bounds__(256) void k_gemm(const float* __restrict__ A,
                                              const float* __restrict__ W,
                                              float* __restrict__ out, int M) {
    __shared__ float sA[32 * K];
    const int t = threadIdx.x;
    const int row0 = blockIdx.x * 32;

    for (int idx = t; idx < 32 * K; idx += 256) {
        float v = 0.0f;
        if (row0 + idx / K < M) v = A[(size_t)row0 * K + idx];
        sA[idx] = RELU_IN ? fmaxf(v, 0.0f) : v;
    }
    __syncthreads();

    float acc[32];
#pragma unroll
    for (int r = 0; r < 32; ++r) acc[r] = 0.0f;

    const int c = t;  // 0..255
    for (int k0 = 0; k0 < K; k0 += 4) {
        const float w0 = W[(k0 + 0) * HID + c];
        const float w1 = W[(k0 + 1) * HID + c];
        const float w2 = W[(k0 + 2) * HID + c];
        const float w3 = W[(k0 + 3) * HID + c];
#pragma unroll
        for (int r = 0; r < 32; ++r) {
            const float4 a = *(const float4*)&sA[r * K + k0];  // broadcast read
            acc[r] += a.x * w0;
            acc[r] += a.y * w1;
            acc[r] += a.z * w2;
            acc[r] += a.w * w3;
        }
    }

    for (int r = 0; r < 32; ++r) {
        const int row = row0 + r;
        if (row < M) out[(size_t)row * HID + c] = acc[r];
    }
}

// ---------------- pull-mode aggregation (no atomics) ----------------
// One wave per node v: out[v] = b + dinv[v]^2 * h[v] + sum_in dinv[s]*dinv[v]*h[s]
// Lane l owns channels [4l, 4l+4): each row access is 64 lanes x 16B = 1KB coalesced.
__global__ __launch_bounds__(256) void k_aggregate(const float* __restrict__ h,
                                                   const int* __restrict__ row_ptr,
                                                   const int* __restrict__ csr_src,
                                                   const float* __restrict__ dinv,
                                                   const float* __restrict__ bias,
                                                   float* __restrict__ out, int n) {
    const int wave = (blockIdx.x * 256 + threadIdx.x) >> 6;
    const int lane = threadIdx.x & 63;
    if (wave >= n) return;
    const int v = wave;
    const float dv = dinv[v];

    const float4 hv = *(const float4*)(h + (size_t)v * HID + lane * 4);
    const float4 b4 = *(const float4*)(bias + lane * 4);
    const float s2 = dv * dv;
    float ax = b4.x + s2 * hv.x;
    float ay = b4.y + s2 * hv.y;
    float az = b4.z + s2 * hv.z;
    float aw = b4.w + s2 * hv.w;

    const int beg = row_ptr[v];
    const int end = row_ptr[v + 1];
    int i = beg;
    for (; i + 1 < end; i += 2) {  // 2-way ILP to overlap gather latency
        const int s0 = csr_src[i];
        const int s1 = csr_src[i + 1];
        const float n0 = dv * dinv[s0];
        const float n1 = dv * dinv[s1];
        const float4 m0 = *(const float4*)(h + (size_t)s0 * HID + lane * 4);
        const float4 m1 = *(const float4*)(h + (size_t)s1 * HID + lane * 4);
        ax = fmaf(n0, m0.x, fmaf(n1, m1.x, ax));
        ay = fmaf(n0, m0.y, fmaf(n1, m1.y, ay));
        az = fmaf(n0, m0.z, fmaf(n1, m1.z, az));
        aw = fmaf(n0, m0.w, fmaf(n1, m1.w, aw));
    }
    if (i < end) {
        const int s0 = csr_src[i];
        const float n0 = dv * dinv[s0];
        const float4 m0 = *(const float4*)(h + (size_t)s0 * HID + lane * 4);
        ax = fmaf(n0, m0.x, ax);
        ay = fmaf(n0, m0.y, ay);
        az = fmaf(n0, m0.z, az);
        aw = fmaf(n0, m0.w, aw);
    }
    float4 o = {ax, ay, az, aw};
    *(float4*)(out + (size_t)v * HID + lane * 4) = o;
}

// ---------------- mean pool over sorted batch (binary search, no atomics) ----------------
__global__ void k_pool(const float* __restrict__ h, const int* __restrict__ batch,
                       float* __restrict__ pooled, int n) {
    const int g = blockIdx.x;
    const int c = threadIdx.x;  // 256
    int a = 0, b = n;
    while (a < b) { int m = (a + b) >> 1; if (batch[m] < g) a = m + 1; else b = m; }
    const int start = a;
    b = n;
    while (a < b) { int m = (a + b) >> 1; if (batch[m] < g + 1) a = m + 1; else b = m; }
    const int end = a;
    float sum = 0.0f;
    for (int v = start; v < end; ++v) sum += fmaxf(h[(size_t)v * HID + c], 0.0f);
    const float cnt = (float)(end - start);
    pooled[g * HID + c] = sum / fmaxf(cnt, 1.0f);
}

// ---------------- final FC: out[G,128] = pooled[G,256] @ Wfc + bfc ----------------
__global__ void k_fc(const float* __restrict__ pooled, const float* __restrict__ W,
                     const float* __restrict__ b, float* __restrict__ out) {
    const int g = blockIdx.x;
    const int c = threadIdx.x;  // 128
    float acc = b[c];
    const float* p = pooled + g * HID;
    for (int k = 0; k < HID; ++k) acc += p[k] * W[k * OUTC + c];
    out[g * OUTC + c] = acc;
}

extern "C" void kernel_launch(void* const* d_in, const int* in_sizes, int n_in,
                              void* d_out, int out_size, void* d_ws, size_t ws_size,
                              hipStream_t stream) {
    const float* x   = (const float*)d_in[0];
    const int*   ei  = (const int*)d_in[1];
    const int*   bat = (const int*)d_in[2];
    const float* W1  = (const float*)d_in[3];
    const float* b1  = (const float*)d_in[4];
    const float* W2  = (const float*)d_in[5];
    const float* b2  = (const float*)d_in[6];
    const float* Wfc = (const float*)d_in[7];
    const float* bfc = (const float*)d_in[8];
    float* out = (float*)d_out;

    const int n = in_sizes[2];       // 50000 nodes
    const int e = in_sizes[1] / 2;   // 800000 edges
    const int* src = ei;
    const int* dst = ei + e;

    // Workspace layout
    char* wsb = (char*)d_ws;
    int*   cnt     = (int*)wsb;                       wsb += (size_t)n * 4;       // histogram, then cursor
    int*   row_ptr = (int*)wsb;                       wsb += (size_t)(n + 1) * 4;
    int*   csr_src = (int*)wsb;                       wsb += (size_t)e * 4;
    float* dinv    = (float*)wsb;                     wsb += (size_t)n * 4;
    float* bufA    = (float*)wsb;                     wsb += (size_t)n * HID * 4; // h
    float* bufB    = (float*)wsb;                     wsb += (size_t)n * HID * 4; // aggregated
    float* pooled  = (float*)wsb;

    const int TB = 256;
    // CSR build (shared by both layers)
    hipMemsetAsync(cnt, 0, (size_t)n * 4, stream);
    k_hist<<<(e + TB - 1) / TB, TB, 0, stream>>>(dst, cnt, e);
    k_dinv<<<(n + TB - 1) / TB, TB, 0, stream>>>(cnt, dinv, n);
    k_scan<<<1, 1024, 0, stream>>>(cnt, row_ptr, n);
    k_fill<<<(e + TB - 1) / TB, TB, 0, stream>>>(src, dst, row_ptr, cnt, csr_src, e);

    const int gemm_blocks = (n + 31) / 32;
    const int agg_blocks = (n + 3) / 4;  // 4 waves (nodes) per 256-thread block

    // Layer 1
    k_gemm<128, false><<<gemm_blocks, TB, 0, stream>>>(x, W1, bufA, n);
    k_aggregate<<<agg_blocks, TB, 0, stream>>>(bufA, row_ptr, csr_src, dinv, b1, bufB, n);

    // Layer 2
    k_gemm<256, true><<<gemm_blocks, TB, 0, stream>>>(bufB, W2, bufA, n);
    k_aggregate<<<agg_blocks, TB, 0, stream>>>(bufA, row_ptr, csr_src, dinv, b2, bufB, n);

    // Pool (relu fused) + FC
    k_pool<<<128, 256, 0, stream>>>(bufB, bat, pooled, n);
    k_fc<<<128, 128, 0, stream>>>(pooled, Wfc, bfc, out);
}

// Round 5
// 624.489 us; speedup vs baseline: 9.3445x; 1.4208x over previous
//
#include <hip/hip_runtime.h>

// Problem constants (fixed by the reference)
#define HID 256
#define OUTC 128

typedef __attribute__((ext_vector_type(8))) short short8;     // 8 bf16 = 4 VGPRs (MFMA A/B frag)
typedef __attribute__((ext_vector_type(4))) float floatx4;    // MFMA C/D frag

__device__ __forceinline__ unsigned short f2bf(float f) {
    unsigned int u = __float_as_uint(f);
    unsigned int r = (u + 0x7FFFu + ((u >> 16) & 1u)) >> 16;  // RNE
    return (unsigned short)r;
}

__device__ __forceinline__ float4 bf4_to_f4(uint2 u) {
    float4 f;
    f.x = __uint_as_float(u.x << 16);
    f.y = __uint_as_float(u.x & 0xFFFF0000u);
    f.z = __uint_as_float(u.y << 16);
    f.w = __uint_as_float(u.y & 0xFFFF0000u);
    return f;
}

// ---------------- CSR build: histogram / dinv / scan / fill ----------------
__global__ void k_hist(const int* __restrict__ dst, int* __restrict__ cnt, int e) {
    int i = blockIdx.x * blockDim.x + threadIdx.x;
    if (i < e) atomicAdd(&cnt[dst[i]], 1);
}

__global__ void k_dinv(const int* __restrict__ cnt, float* __restrict__ dinv, int n) {
    int i = blockIdx.x * blockDim.x + threadIdx.x;
    if (i < n) dinv[i] = rsqrtf((float)cnt[i] + 1.0f);  // +1 self loop
}

// Single-block exclusive scan of cnt -> row_ptr; resets cnt to 0 (reused as cursor).
__global__ __launch_bounds__(1024) void k_scan(int* __restrict__ cnt, int* __restrict__ row_ptr, int n) {
    __shared__ int sdata[1024];
    __shared__ int s_running;
    const int t = threadIdx.x;
    if (t == 0) s_running = 0;
    __syncthreads();
    for (int base = 0; base < n; base += 1024) {
        const int i = base + t;
        const int v = (i < n) ? cnt[i] : 0;
        sdata[t] = v;
        __syncthreads();
        for (int off = 1; off < 1024; off <<= 1) {
            int add = (t >= off) ? sdata[t - off] : 0;
            __syncthreads();
            sdata[t] += add;
            __syncthreads();
        }
        if (i < n) { row_ptr[i] = s_running + sdata[t] - v; cnt[i] = 0; }
        __syncthreads();
        if (t == 1023) s_running += sdata[1023];
        __syncthreads();
    }
    if (t == 0) row_ptr[n] = s_running;
}

__global__ void k_fill(const int* __restrict__ src, const int* __restrict__ dst,
                       const int* __restrict__ row_ptr, int* __restrict__ cursor,
                       int* __restrict__ csr_src, int e) {
    int i = blockIdx.x * blockDim.x + threadIdx.x;
    if (i < e) {
        const int d = dst[i];
        const int pos = row_ptr[d] + atomicAdd(&cursor[d], 1);
        csr_src[pos] = src[i];
    }
}

// ---------------- W transpose + bf16 convert: Wt[n][k] = bf16(W[k][n]) ----------------
__global__ void k_convW(const float* __restrict__ W, unsigned short* __restrict__ Wt, int K) {
    int id = blockIdx.x * 256 + threadIdx.x;  // id = n*K + k
    if (id < K * HID) {
        int n = id / K;
        int k = id - n * K;
        Wt[id] = f2bf(W[k * HID + n]);
    }
}

// ---------------- MFMA GEMM: h[M,256](bf16) = A[M,K] @ W[K,256] ----------------
// Block = 4 waves, M-tile = 16 (M % 16 == 0). Wave w owns N-cols [64w, 64w+64) as
// 4 x mfma_f32_16x16x32_bf16. A staged in padded LDS (bf16); B from n-major bf16 Wt (L2).
// IT = float (fp32 input, converted) or unsigned short (bf16 input, raw copy).
template <int K, typename IT>
__global__ __launch_bounds__(256) void k_gemm_mfma(const IT* __restrict__ A,
                                                   const unsigned short* __restrict__ Wt,
                                                   unsigned short* __restrict__ h_out, int M) {
    constexpr int LDA = K + 8;  // +16B pad: breaks power-of-2 LDS stride
    __shared__ unsigned short sA[16 * LDA];
    const int t = threadIdx.x;
    const int row0 = blockIdx.x * 16;

    // ---- stage 16 x K tile into LDS as bf16 ----
    {
        const int r = t >> 4;                 // 0..15
        const int c0 = (t & 15) * (K / 16);   // K=128 -> 8 cols/thread, K=256 -> 16
        const IT* srcp = A + (size_t)(row0 + r) * K + c0;
        unsigned short* dstp = &sA[r * LDA + c0];
        if constexpr (sizeof(IT) == 4) {
            // fp32 -> bf16: 8 floats -> one 16B LDS store
#pragma unroll
            for (int j = 0; j < K / 16; j += 8) {
                const float4 v0 = *(const float4*)((const float*)srcp + j);
                const float4 v1 = *(const float4*)((const float*)srcp + j + 4);
                uint4 pk;
                pk.x = (unsigned)f2bf(v0.x) | ((unsigned)f2bf(v0.y) << 16);
                pk.y = (unsigned)f2bf(v0.z) | ((unsigned)f2bf(v0.w) << 16);
                pk.z = (unsigned)f2bf(v1.x) | ((unsigned)f2bf(v1.y) << 16);
                pk.w = (unsigned)f2bf(v1.z) | ((unsigned)f2bf(v1.w) << 16);
                *(uint4*)(dstp + j) = pk;
            }
        } else {
            // bf16 -> bf16 raw copy, 16B chunks
#pragma unroll
            for (int j = 0; j < K / 16; j += 8) {
                *(uint4*)(dstp + j) = *(const uint4*)((const unsigned short*)srcp + j);
            }
        }
    }
    __syncthreads();

    const int wv = t >> 6;       // wave 0..3
    const int lane = t & 63;
    const int m16 = lane & 15;   // A row / D col
    const int quad = lane >> 4;  // 0..3

    floatx4 acc0 = {0.f, 0.f, 0.f, 0.f};
    floatx4 acc1 = {0.f, 0.f, 0.f, 0.f};
    floatx4 acc2 = {0.f, 0.f, 0.f, 0.f};
    floatx4 acc3 = {0.f, 0.f, 0.f, 0.f};

    const unsigned short* ap = &sA[m16 * LDA + quad * 8];
    const unsigned short* bp = Wt + (size_t)(wv * 64 + m16) * K + quad * 8;

#pragma unroll
    for (int k0 = 0; k0 < K; k0 += 32) {
        const short8 a = *(const short8*)(ap + k0);
        const short8 b0 = *(const short8*)(bp + 0 * 16 * K + k0);
        const short8 b1 = *(const short8*)(bp + 1 * 16 * K + k0);
        const short8 b2 = *(const short8*)(bp + 2 * 16 * K + k0);
        const short8 b3 = *(const short8*)(bp + 3 * 16 * K + k0);
        acc0 = __builtin_amdgcn_mfma_f32_16x16x32_bf16(a, b0, acc0, 0, 0, 0);
        acc1 = __builtin_amdgcn_mfma_f32_16x16x32_bf16(a, b1, acc1, 0, 0, 0);
        acc2 = __builtin_amdgcn_mfma_f32_16x16x32_bf16(a, b2, acc2, 0, 0, 0);
        acc3 = __builtin_amdgcn_mfma_f32_16x16x32_bf16(a, b3, acc3, 0, 0, 0);
    }

    // D layout: col = lane&15, row = quad*4 + reg
    const int nbase = wv * 64 + m16;
#pragma unroll
    for (int j = 0; j < 4; ++j) {
        const size_t row = (size_t)(row0 + quad * 4 + j);
        h_out[row * HID + nbase + 0]  = f2bf(acc0[j]);
        h_out[row * HID + nbase + 16] = f2bf(acc1[j]);
        h_out[row * HID + nbase + 32] = f2bf(acc2[j]);
        h_out[row * HID + nbase + 48] = f2bf(acc3[j]);
    }
}

// ---------------- pull-mode aggregation (no atomics), bf16 gather ----------------
// One wave per node v: out[v] = b + dinv[v]^2*h[v] + sum_in dinv[s]*dinv[v]*h[s]
// Lane l owns channels [4l,4l+4): each row gather = 64 lanes x 8B = 512B coalesced.
// BF16_RELU_OUT: write relu'd bf16 (feeds next GEMM); else write fp32.
template <bool BF16_RELU_OUT>
__global__ __launch_bounds__(256) void k_aggregate(const unsigned short* __restrict__ h,
                                                   const int* __restrict__ row_ptr,
                                                   const int* __restrict__ csr_src,
                                                   const float* __restrict__ dinv,
                                                   const float* __restrict__ bias,
                                                   void* __restrict__ outp, int n) {
    const int v = (blockIdx.x * 256 + threadIdx.x) >> 6;
    const int lane = threadIdx.x & 63;
    if (v >= n) return;
    const float dv = dinv[v];

    const float4 hv = bf4_to_f4(*(const uint2*)(h + (size_t)v * HID + lane * 4));
    const float4 b4 = *(const float4*)(bias + lane * 4);
    const float s2 = dv * dv;
    float ax = b4.x + s2 * hv.x;
    float ay = b4.y + s2 * hv.y;
    float az = b4.z + s2 * hv.z;
    float aw = b4.w + s2 * hv.w;

    const int beg = row_ptr[v];
    const int end = row_ptr[v + 1];
    int i = beg;
    for (; i + 1 < end; i += 2) {  // 2-way ILP to overlap gather latency
        const int s0 = csr_src[i];
        const int s1 = csr_src[i + 1];
        const float n0 = dv * dinv[s0];
        const float n1 = dv * dinv[s1];
        const float4 m0 = bf4_to_f4(*(const uint2*)(h + (size_t)s0 * HID + lane * 4));
        const float4 m1 = bf4_to_f4(*(const uint2*)(h + (size_t)s1 * HID + lane * 4));
        ax = fmaf(n0, m0.x, fmaf(n1, m1.x, ax));
        ay = fmaf(n0, m0.y, fmaf(n1, m1.y, ay));
        az = fmaf(n0, m0.z, fmaf(n1, m1.z, az));
        aw = fmaf(n0, m0.w, fmaf(n1, m1.w, aw));
    }
    if (i < end) {
        const int s0 = csr_src[i];
        const float n0 = dv * dinv[s0];
        const float4 m0 = bf4_to_f4(*(const uint2*)(h + (size_t)s0 * HID + lane * 4));
        ax = fmaf(n0, m0.x, ax);
        ay = fmaf(n0, m0.y, ay);
        az = fmaf(n0, m0.z, az);
        aw = fmaf(n0, m0.w, aw);
    }

    if constexpr (BF16_RELU_OUT) {
        uint2 o;
        o.x = (unsigned)f2bf(fmaxf(ax, 0.f)) | ((unsigned)f2bf(fmaxf(ay, 0.f)) << 16);
        o.y = (unsigned)f2bf(fmaxf(az, 0.f)) | ((unsigned)f2bf(fmaxf(aw, 0.f)) << 16);
        *(uint2*)((unsigned short*)outp + (size_t)v * HID + lane * 4) = o;
    } else {
        float4 o = {ax, ay, az, aw};
        *(float4*)((float*)outp + (size_t)v * HID + lane * 4) = o;
    }
}

// ---------------- mean pool over sorted batch (binary search, relu fused) ----------------
__global__ void k_pool(const float* __restrict__ h, const int* __restrict__ batch,
                       float* __restrict__ pooled, int n) {
    const int g = blockIdx.x;
    const int c = threadIdx.x;  // 256
    int a = 0, b = n;
    while (a < b) { int m = (a + b) >> 1; if (batch[m] < g) a = m + 1; else b = m; }
    const int start = a;
    b = n;
    while (a < b) { int m = (a + b) >> 1; if (batch[m] < g + 1) a = m + 1; else b = m; }
    const int end = a;
    float sum = 0.0f;
    for (int v = start; v < end; ++v) sum += fmaxf(h[(size_t)v * HID + c], 0.0f);
    const float cnt = (float)(end - start);
    pooled[g * HID + c] = sum / fmaxf(cnt, 1.0f);
}

// ---------------- final FC: out[G,128] = pooled[G,256] @ Wfc + bfc ----------------
__global__ void k_fc(const float* __restrict__ pooled, const float* __restrict__ W,
                     const float* __restrict__ b, float* __restrict__ out) {
    const int g = blockIdx.x;
    const int c = threadIdx.x;  // 128
    float acc = b[c];
    const float* p = pooled + g * HID;
    for (int k = 0; k < HID; ++k) acc += p[k] * W[k * OUTC + c];
    out[g * OUTC + c] = acc;
}

extern "C" void kernel_launch(void* const* d_in, const int* in_sizes, int n_in,
                              void* d_out, int out_size, void* d_ws, size_t ws_size,
                              hipStream_t stream) {
    const float* x   = (const float*)d_in[0];
    const int*   ei  = (const int*)d_in[1];
    const int*   bat = (const int*)d_in[2];
    const float* W1  = (const float*)d_in[3];
    const float* b1  = (const float*)d_in[4];
    const float* W2  = (const float*)d_in[5];
    const float* b2  = (const float*)d_in[6];
    const float* Wfc = (const float*)d_in[7];
    const float* bfc = (const float*)d_in[8];
    float* out = (float*)d_out;

    const int n = in_sizes[2];       // 50000 nodes (50000 % 16 == 0)
    const int e = in_sizes[1] / 2;   // 800000 edges
    const int* src = ei;
    const int* dst = ei + e;

    // Workspace layout
    char* wsb = (char*)d_ws;
    int*   cnt     = (int*)wsb;                        wsb += (size_t)n * 4;
    int*   row_ptr = (int*)wsb;                        wsb += (size_t)(n + 1) * 4;
    int*   csr_src = (int*)wsb;                        wsb += (size_t)e * 4;
    float* dinv    = (float*)wsb;                      wsb += (size_t)n * 4;
    unsigned short* Wt1 = (unsigned short*)wsb;        wsb += (size_t)128 * HID * 2;
    unsigned short* Wt2 = (unsigned short*)wsb;        wsb += (size_t)HID * HID * 2;
    unsigned short* bufX = (unsigned short*)wsb;       wsb += (size_t)n * HID * 2;  // h1, then h2
    unsigned short* bufY = (unsigned short*)wsb;       wsb += (size_t)n * HID * 2;  // relu(agg1)
    float* bufB   = (float*)wsb;                       wsb += (size_t)n * HID * 4;  // agg2 (fp32)
    float* pooled = (float*)wsb;

    const int TB = 256;
    // CSR build (shared by both layers)
    hipMemsetAsync(cnt, 0, (size_t)n * 4, stream);
    k_hist<<<(e + TB - 1) / TB, TB, 0, stream>>>(dst, cnt, e);
    k_dinv<<<(n + TB - 1) / TB, TB, 0, stream>>>(cnt, dinv, n);
    k_scan<<<1, 1024, 0, stream>>>(cnt, row_ptr, n);
    k_fill<<<(e + TB - 1) / TB, TB, 0, stream>>>(src, dst, row_ptr, cnt, csr_src, e);

    // Weight transpose + bf16 convert
    k_convW<<<128, TB, 0, stream>>>(W1, Wt1, 128);
    k_convW<<<256, TB, 0, stream>>>(W2, Wt2, 256);

    const int gemm_blocks = n / 16;
    const int agg_blocks = (n + 3) / 4;

    // Layer 1: h1 = x @ W1 (bf16 MFMA); agg1 -> relu bf16
    k_gemm_mfma<128, float><<<gemm_blocks, TB, 0, stream>>>(x, Wt1, bufX, n);
    k_aggregate<true><<<agg_blocks, TB, 0, stream>>>(bufX, row_ptr, csr_src, dinv, b1, bufY, n);

    // Layer 2: h2 = relu(agg1) @ W2; agg2 -> fp32
    k_gemm_mfma<256, unsigned short><<<gemm_blocks, TB, 0, stream>>>(bufY, Wt2, bufX, n);
    k_aggregate<false><<<agg_blocks, TB, 0, stream>>>(bufX, row_ptr, csr_src, dinv, b2, bufB, n);

    // Pool (relu fused) + FC
    k_pool<<<128, 256, 0, stream>>>(bufB, bat, pooled, n);
    k_fc<<<128, 128, 0, stream>>>(pooled, Wfc, bfc, out);
}

// Round 6
// 543.169 us; speedup vs baseline: 10.7435x; 1.1497x over previous
//
#include <hip/hip_runtime.h>

// Problem constants (fixed by the reference)
#define HID 256
#define OUTC 128

typedef __attribute__((ext_vector_type(8))) short short8;     // 8 bf16 = 4 VGPRs (MFMA A/B frag)
typedef __attribute__((ext_vector_type(4))) float floatx4;    // MFMA C/D frag

__device__ __forceinline__ unsigned short f2bf(float f) {
    unsigned int u = __float_as_uint(f);
    unsigned int r = (u + 0x7FFFu + ((u >> 16) & 1u)) >> 16;  // RNE
    return (unsigned short)r;
}

__device__ __forceinline__ float4 bf4_to_f4(uint2 u) {
    float4 f;
    f.x = __uint_as_float(u.x << 16);
    f.y = __uint_as_float(u.x & 0xFFFF0000u);
    f.z = __uint_as_float(u.y << 16);
    f.w = __uint_as_float(u.y & 0xFFFF0000u);
    return f;
}

// ---------------- CSR build: histogram / dinv / scan / fill ----------------
__global__ void k_hist(const int* __restrict__ dst, int* __restrict__ cnt, int e) {
    int i = blockIdx.x * blockDim.x + threadIdx.x;
    if (i < e) atomicAdd(&cnt[dst[i]], 1);
}

__global__ void k_dinv(const int* __restrict__ cnt, float* __restrict__ dinv, int n) {
    int i = blockIdx.x * blockDim.x + threadIdx.x;
    if (i < n) dinv[i] = rsqrtf((float)cnt[i] + 1.0f);  // +1 self loop
}

// Single-block exclusive scan of cnt -> row_ptr; resets cnt to 0 (reused as cursor).
__global__ __launch_bounds__(1024) void k_scan(int* __restrict__ cnt, int* __restrict__ row_ptr, int n) {
    __shared__ int sdata[1024];
    __shared__ int s_running;
    const int t = threadIdx.x;
    if (t == 0) s_running = 0;
    __syncthreads();
    for (int base = 0; base < n; base += 1024) {
        const int i = base + t;
        const int v = (i < n) ? cnt[i] : 0;
        sdata[t] = v;
        __syncthreads();
        for (int off = 1; off < 1024; off <<= 1) {
            int add = (t >= off) ? sdata[t - off] : 0;
            __syncthreads();
            sdata[t] += add;
            __syncthreads();
        }
        if (i < n) { row_ptr[i] = s_running + sdata[t] - v; cnt[i] = 0; }
        __syncthreads();
        if (t == 1023) s_running += sdata[1023];
        __syncthreads();
    }
    if (t == 0) row_ptr[n] = s_running;
}

__global__ void k_fill(const int* __restrict__ src, const int* __restrict__ dst,
                       const int* __restrict__ row_ptr, int* __restrict__ cursor,
                       int* __restrict__ csr_src, int e) {
    int i = blockIdx.x * blockDim.x + threadIdx.x;
    if (i < e) {
        const int d = dst[i];
        const int pos = row_ptr[d] + atomicAdd(&cursor[d], 1);
        csr_src[pos] = src[i];
    }
}

// ---------------- W transpose + bf16 convert: Wt[n][k] = bf16(W[k][n]) ----------------
__global__ void k_convW(const float* __restrict__ W, unsigned short* __restrict__ Wt, int K) {
    int id = blockIdx.x * 256 + threadIdx.x;  // id = n*K + k
    if (id < K * HID) {
        int n = id / K;
        int k = id - n * K;
        Wt[id] = f2bf(W[k * HID + n]);
    }
}

// ---------------- MFMA GEMM: h[M,256](bf16) = A[M,K] @ W[K,256] ----------------
// Block = 4 waves, M-tile = 16 (M % 16 == 0). Wave w owns N-cols [64w, 64w+64) as
// 4 x mfma_f32_16x16x32_bf16. A staged in padded LDS (bf16); B from n-major bf16 Wt (L2).
// IT = float (fp32 input, converted) or unsigned short (bf16 input, raw copy).
template <int K, typename IT>
__global__ __launch_bounds__(256) void k_gemm_mfma(const IT* __restrict__ A,
                                                   const unsigned short* __restrict__ Wt,
                                                   unsigned short* __restrict__ h_out, int M) {
    constexpr int LDA = K + 8;  // +16B pad: breaks power-of-2 LDS stride
    __shared__ unsigned short sA[16 * LDA];
    const int t = threadIdx.x;
    const int row0 = blockIdx.x * 16;

    // ---- stage 16 x K tile into LDS as bf16 ----
    {
        const int r = t >> 4;                 // 0..15
        const int c0 = (t & 15) * (K / 16);   // K=128 -> 8 cols/thread, K=256 -> 16
        const IT* srcp = A + (size_t)(row0 + r) * K + c0;
        unsigned short* dstp = &sA[r * LDA + c0];
        if constexpr (sizeof(IT) == 4) {
            // fp32 -> bf16: 8 floats -> one 16B LDS store
#pragma unroll
            for (int j = 0; j < K / 16; j += 8) {
                const float4 v0 = *(const float4*)((const float*)srcp + j);
                const float4 v1 = *(const float4*)((const float*)srcp + j + 4);
                uint4 pk;
                pk.x = (unsigned)f2bf(v0.x) | ((unsigned)f2bf(v0.y) << 16);
                pk.y = (unsigned)f2bf(v0.z) | ((unsigned)f2bf(v0.w) << 16);
                pk.z = (unsigned)f2bf(v1.x) | ((unsigned)f2bf(v1.y) << 16);
                pk.w = (unsigned)f2bf(v1.z) | ((unsigned)f2bf(v1.w) << 16);
                *(uint4*)(dstp + j) = pk;
            }
        } else {
            // bf16 -> bf16 raw copy, 16B chunks
#pragma unroll
            for (int j = 0; j < K / 16; j += 8) {
                *(uint4*)(dstp + j) = *(const uint4*)((const unsigned short*)srcp + j);
            }
        }
    }
    __syncthreads();

    const int wv = t >> 6;       // wave 0..3
    const int lane = t & 63;
    const int m16 = lane & 15;   // A row / D col
    const int quad = lane >> 4;  // 0..3

    floatx4 acc0 = {0.f, 0.f, 0.f, 0.f};
    floatx4 acc1 = {0.f, 0.f, 0.f, 0.f};
    floatx4 acc2 = {0.f, 0.f, 0.f, 0.f};
    floatx4 acc3 = {0.f, 0.f, 0.f, 0.f};

    const unsigned short* ap = &sA[m16 * LDA + quad * 8];
    const unsigned short* bp = Wt + (size_t)(wv * 64 + m16) * K + quad * 8;

#pragma unroll
    for (int k0 = 0; k0 < K; k0 += 32) {
        const short8 a = *(const short8*)(ap + k0);
        const short8 b0 = *(const short8*)(bp + 0 * 16 * K + k0);
        const short8 b1 = *(const short8*)(bp + 1 * 16 * K + k0);
        const short8 b2 = *(const short8*)(bp + 2 * 16 * K + k0);
        const short8 b3 = *(const short8*)(bp + 3 * 16 * K + k0);
        acc0 = __builtin_amdgcn_mfma_f32_16x16x32_bf16(a, b0, acc0, 0, 0, 0);
        acc1 = __builtin_amdgcn_mfma_f32_16x16x32_bf16(a, b1, acc1, 0, 0, 0);
        acc2 = __builtin_amdgcn_mfma_f32_16x16x32_bf16(a, b2, acc2, 0, 0, 0);
        acc3 = __builtin_amdgcn_mfma_f32_16x16x32_bf16(a, b3, acc3, 0, 0, 0);
    }

    // D layout: col = lane&15, row = quad*4 + reg
    const int nbase = wv * 64 + m16;
#pragma unroll
    for (int j = 0; j < 4; ++j) {
        const size_t row = (size_t)(row0 + quad * 4 + j);
        h_out[row * HID + nbase + 0]  = f2bf(acc0[j]);
        h_out[row * HID + nbase + 16] = f2bf(acc1[j]);
        h_out[row * HID + nbase + 32] = f2bf(acc2[j]);
        h_out[row * HID + nbase + 48] = f2bf(acc3[j]);
    }
}

// ---------------- pull-mode aggregation (no atomics), bf16 gather ----------------
// One wave per node v: out[v] = b + dinv[v]^2*h[v] + sum_in dinv[s]*dinv[v]*h[s]
// Lane l owns channels [4l,4l+4): each row gather = 64 lanes x 8B = 512B coalesced.
// BF16_RELU_OUT: write relu'd bf16 (feeds next GEMM); else write fp32.
template <bool BF16_RELU_OUT>
__global__ __launch_bounds__(256) void k_aggregate(const unsigned short* __restrict__ h,
                                                   const int* __restrict__ row_ptr,
                                                   const int* __restrict__ csr_src,
                                                   const float* __restrict__ dinv,
                                                   const float* __restrict__ bias,
                                                   void* __restrict__ outp, int n) {
    const int v = (blockIdx.x * 256 + threadIdx.x) >> 6;
    const int lane = threadIdx.x & 63;
    if (v >= n) return;
    const float dv = dinv[v];

    const float4 hv = bf4_to_f4(*(const uint2*)(h + (size_t)v * HID + lane * 4));
    const float4 b4 = *(const float4*)(bias + lane * 4);
    const float s2 = dv * dv;
    float ax = b4.x + s2 * hv.x;
    float ay = b4.y + s2 * hv.y;
    float az = b4.z + s2 * hv.z;
    float aw = b4.w + s2 * hv.w;

    const int beg = row_ptr[v];
    const int end = row_ptr[v + 1];
    int i = beg;
    for (; i + 1 < end; i += 2) {  // 2-way ILP to overlap gather latency
        const int s0 = csr_src[i];
        const int s1 = csr_src[i + 1];
        const float n0 = dv * dinv[s0];
        const float n1 = dv * dinv[s1];
        const float4 m0 = bf4_to_f4(*(const uint2*)(h + (size_t)s0 * HID + lane * 4));
        const float4 m1 = bf4_to_f4(*(const uint2*)(h + (size_t)s1 * HID + lane * 4));
        ax = fmaf(n0, m0.x, fmaf(n1, m1.x, ax));
        ay = fmaf(n0, m0.y, fmaf(n1, m1.y, ay));
        az = fmaf(n0, m0.z, fmaf(n1, m1.z, az));
        aw = fmaf(n0, m0.w, fmaf(n1, m1.w, aw));
    }
    if (i < end) {
        const int s0 = csr_src[i];
        const float n0 = dv * dinv[s0];
        const float4 m0 = bf4_to_f4(*(const uint2*)(h + (size_t)s0 * HID + lane * 4));
        ax = fmaf(n0, m0.x, ax);
        ay = fmaf(n0, m0.y, ay);
        az = fmaf(n0, m0.z, az);
        aw = fmaf(n0, m0.w, aw);
    }

    if constexpr (BF16_RELU_OUT) {
        uint2 o;
        o.x = (unsigned)f2bf(fmaxf(ax, 0.f)) | ((unsigned)f2bf(fmaxf(ay, 0.f)) << 16);
        o.y = (unsigned)f2bf(fmaxf(az, 0.f)) | ((unsigned)f2bf(fmaxf(aw, 0.f)) << 16);
        *(uint2*)((unsigned short*)outp + (size_t)v * HID + lane * 4) = o;
    } else {
        float4 o = {ax, ay, az, aw};
        *(float4*)((float*)outp + (size_t)v * HID + lane * 4) = o;
    }
}

// ---------------- pool stage 1: chunked partial sums (relu fused) ----------------
// Block b handles nodes [64b, 64b+64); thread t = channel t. batch sorted ->
// graph boundaries are block-uniform; flush one atomicAdd per (segment, channel).
#define POOL_CHUNK 64
__global__ __launch_bounds__(256) void k_pool_partial(const float* __restrict__ h,
                                                      const int* __restrict__ batch,
                                                      float* __restrict__ pooled_sum, int n) {
    const int c = threadIdx.x;  // 256
    const int v0 = blockIdx.x * POOL_CHUNK;
    const int v1 = min(v0 + POOL_CHUNK, n);
    if (v0 >= n) return;
    int cur_g = batch[v0];
    float sum = 0.0f;
    for (int v = v0; v < v1; ++v) {
        const int g = batch[v];            // block-uniform
        const float val = fmaxf(h[(size_t)v * HID + c], 0.0f);
        if (g != cur_g) {                  // uniform branch
            atomicAdd(&pooled_sum[cur_g * HID + c], sum);
            sum = 0.0f;
            cur_g = g;
        }
        sum += val;
    }
    atomicAdd(&pooled_sum[cur_g * HID + c], sum);
}

// ---------------- final FC with fused mean: out[g] = (sum[g] @ Wfc)/cnt + bfc ----------------
__global__ void k_fc(const float* __restrict__ pooled_sum, const int* __restrict__ batch,
                     const float* __restrict__ W, const float* __restrict__ b,
                     float* __restrict__ out, int n) {
    const int g = blockIdx.x;
    const int c = threadIdx.x;  // 128
    // count nodes in graph g via uniform binary searches (batch sorted)
    int a = 0, hi = n;
    while (a < hi) { int m = (a + hi) >> 1; if (batch[m] < g) a = m + 1; else hi = m; }
    const int start = a;
    hi = n;
    while (a < hi) { int m = (a + hi) >> 1; if (batch[m] < g + 1) a = m + 1; else hi = m; }
    const float cnt = (float)(a - start);

    float acc = 0.0f;
    const float* p = pooled_sum + g * HID;
    for (int k = 0; k < HID; ++k) acc += p[k] * W[k * OUTC + c];
    out[g * OUTC + c] = acc / fmaxf(cnt, 1.0f) + b[c];
}

extern "C" void kernel_launch(void* const* d_in, const int* in_sizes, int n_in,
                              void* d_out, int out_size, void* d_ws, size_t ws_size,
                              hipStream_t stream) {
    const float* x   = (const float*)d_in[0];
    const int*   ei  = (const int*)d_in[1];
    const int*   bat = (const int*)d_in[2];
    const float* W1  = (const float*)d_in[3];
    const float* b1  = (const float*)d_in[4];
    const float* W2  = (const float*)d_in[5];
    const float* b2  = (const float*)d_in[6];
    const float* Wfc = (const float*)d_in[7];
    const float* bfc = (const float*)d_in[8];
    float* out = (float*)d_out;

    const int n = in_sizes[2];       // 50000 nodes (50000 % 16 == 0)
    const int e = in_sizes[1] / 2;   // 800000 edges
    const int* src = ei;
    const int* dst = ei + e;

    // Workspace layout
    char* wsb = (char*)d_ws;
    int*   cnt     = (int*)wsb;                        wsb += (size_t)n * 4;
    int*   row_ptr = (int*)wsb;                        wsb += (size_t)(n + 1) * 4;
    int*   csr_src = (int*)wsb;                        wsb += (size_t)e * 4;
    float* dinv    = (float*)wsb;                      wsb += (size_t)n * 4;
    unsigned short* Wt1 = (unsigned short*)wsb;        wsb += (size_t)128 * HID * 2;
    unsigned short* Wt2 = (unsigned short*)wsb;        wsb += (size_t)HID * HID * 2;
    unsigned short* bufX = (unsigned short*)wsb;       wsb += (size_t)n * HID * 2;  // h1, then h2
    unsigned short* bufY = (unsigned short*)wsb;       wsb += (size_t)n * HID * 2;  // relu(agg1)
    float* bufB   = (float*)wsb;                       wsb += (size_t)n * HID * 4;  // agg2 (fp32)
    float* pooled = (float*)wsb;                       // 128*256 fp32 sums

    const int TB = 256;
    // CSR build (shared by both layers)
    hipMemsetAsync(cnt, 0, (size_t)n * 4, stream);
    hipMemsetAsync(pooled, 0, (size_t)128 * HID * 4, stream);
    k_hist<<<(e + TB - 1) / TB, TB, 0, stream>>>(dst, cnt, e);
    k_dinv<<<(n + TB - 1) / TB, TB, 0, stream>>>(cnt, dinv, n);
    k_scan<<<1, 1024, 0, stream>>>(cnt, row_ptr, n);
    k_fill<<<(e + TB - 1) / TB, TB, 0, stream>>>(src, dst, row_ptr, cnt, csr_src, e);

    // Weight transpose + bf16 convert
    k_convW<<<128, TB, 0, stream>>>(W1, Wt1, 128);
    k_convW<<<256, TB, 0, stream>>>(W2, Wt2, 256);

    const int gemm_blocks = n / 16;
    const int agg_blocks = (n + 3) / 4;

    // Layer 1: h1 = x @ W1 (bf16 MFMA); agg1 -> relu bf16
    k_gemm_mfma<128, float><<<gemm_blocks, TB, 0, stream>>>(x, Wt1, bufX, n);
    k_aggregate<true><<<agg_blocks, TB, 0, stream>>>(bufX, row_ptr, csr_src, dinv, b1, bufY, n);

    // Layer 2: h2 = relu(agg1) @ W2; agg2 -> fp32
    k_gemm_mfma<256, unsigned short><<<gemm_blocks, TB, 0, stream>>>(bufY, Wt2, bufX, n);
    k_aggregate<false><<<agg_blocks, TB, 0, stream>>>(bufX, row_ptr, csr_src, dinv, b2, bufB, n);

    // Pool (relu + mean fused across two kernels) + FC
    k_pool_partial<<<(n + POOL_CHUNK - 1) / POOL_CHUNK, TB, 0, stream>>>(bufB, bat, pooled, n);
    k_fc<<<128, 128, 0, stream>>>(pooled, bat, Wfc, bfc, out, n);
}

// Round 7
// 438.234 us; speedup vs baseline: 13.3160x; 1.2395x over previous
//
#include <hip/hip_runtime.h>

// Problem constants (fixed by the reference)
#define HID 256
#define INC 128
#define OUTC 128

typedef __attribute__((ext_vector_type(8))) short short8;     // 8 bf16 = 4 VGPRs (MFMA A/B frag)
typedef __attribute__((ext_vector_type(4))) float floatx4;    // MFMA C/D frag

__device__ __forceinline__ unsigned short f2bf(float f) {
    unsigned int u = __float_as_uint(f);
    unsigned int r = (u + 0x7FFFu + ((u >> 16) & 1u)) >> 16;  // RNE
    return (unsigned short)r;
}

// ---------------- x -> bf16 convert ----------------
__global__ void k_convX(const float* __restrict__ x, unsigned short* __restrict__ xb, int total4) {
    int i = blockIdx.x * 256 + threadIdx.x;
    if (i < total4) {
        const float4 v = *(const float4*)(x + (size_t)i * 4);
        uint2 o;
        o.x = (unsigned)f2bf(v.x) | ((unsigned)f2bf(v.y) << 16);
        o.y = (unsigned)f2bf(v.z) | ((unsigned)f2bf(v.w) << 16);
        *(uint2*)(xb + (size_t)i * 4) = o;
    }
}

// ---------------- CSR build ----------------
__global__ void k_hist(const int* __restrict__ dst, int* __restrict__ cnt, int e) {
    int i = blockIdx.x * blockDim.x + threadIdx.x;
    if (i < e) atomicAdd(&cnt[dst[i]], 1);
}

__global__ void k_dinv(const int* __restrict__ cnt, float* __restrict__ dinv, int n) {
    int i = blockIdx.x * blockDim.x + threadIdx.x;
    if (i < n) dinv[i] = rsqrtf((float)cnt[i] + 1.0f);  // +1 self loop
}

// Hierarchical exclusive scan: local (per 256-block) -> block sums -> add offsets.
__global__ __launch_bounds__(256) void k_scan_local(const int* __restrict__ cnt,
                                                    int* __restrict__ ex, int* __restrict__ blk_sum, int n) {
    __shared__ int s[256];
    const int t = threadIdx.x;
    const int i = blockIdx.x * 256 + t;
    const int v = (i < n) ? cnt[i] : 0;
    s[t] = v;
    __syncthreads();
    for (int off = 1; off < 256; off <<= 1) {
        int add = (t >= off) ? s[t - off] : 0;
        __syncthreads();
        s[t] += add;
        __syncthreads();
    }
    if (i < n) ex[i] = s[t] - v;
    if (t == 255) blk_sum[blockIdx.x] = s[255];
}

__global__ __launch_bounds__(256) void k_scan_blk(int* __restrict__ blk_sum, int nb) {
    __shared__ int s[256];
    const int t = threadIdx.x;
    const int v = (t < nb) ? blk_sum[t] : 0;
    s[t] = v;
    __syncthreads();
    for (int off = 1; off < 256; off <<= 1) {
        int add = (t >= off) ? s[t - off] : 0;
        __syncthreads();
        s[t] += add;
        __syncthreads();
    }
    if (t < nb) blk_sum[t] = s[t] - v;  // exclusive
}

__global__ void k_scan_add(int* __restrict__ row_ptr, const int* __restrict__ blk_sum,
                           int* __restrict__ cnt, int n, int e) {
    int i = blockIdx.x * 256 + threadIdx.x;
    if (i < n) { row_ptr[i] += blk_sum[i >> 8]; cnt[i] = 0; }  // cnt reset -> fill cursor
    if (i == 0) row_ptr[n] = e;
}

__global__ void k_fill(const int* __restrict__ src, const int* __restrict__ dst,
                       const int* __restrict__ row_ptr, int* __restrict__ cursor,
                       int* __restrict__ csr_src, int e) {
    int i = blockIdx.x * blockDim.x + threadIdx.x;
    if (i < e) {
        const int d = dst[i];
        const int pos = row_ptr[d] + atomicAdd(&cursor[d], 1);
        csr_src[pos] = src[i];
    }
}

// ---------------- W transpose + bf16 convert: Wt[n][k] = bf16(W[k][n]) ----------------
__global__ void k_convW(const float* __restrict__ W, unsigned short* __restrict__ Wt, int K) {
    int id = blockIdx.x * 256 + threadIdx.x;  // id = n*K + k
    if (id < K * HID) {
        int n = id / K;
        int k = id - n * K;
        Wt[id] = f2bf(W[k * HID + n]);
    }
}

// ---------------- pull-mode aggregation (no atomics, no bias): out = A_norm . h ----------------
// One wave per node v: out[v] = dinv[v]^2*h[v] + sum_in dinv[s]*dinv[v]*h[s]
// CH channels bf16; lane owns CH/64 channels -> row gather is 64 lanes x (CH/64*2)B contiguous.
template <int CH>
__global__ __launch_bounds__(256) void k_agg(const unsigned short* __restrict__ h,
                                             const int* __restrict__ row_ptr,
                                             const int* __restrict__ csr_src,
                                             const float* __restrict__ dinv,
                                             unsigned short* __restrict__ out, int n) {
    constexpr int CPL = CH / 64;  // bf16 per lane: 2 or 4
    constexpr int UPL = CPL / 2;  // uints per lane: 1 or 2
    const int v = (blockIdx.x * 256 + threadIdx.x) >> 6;
    const int lane = threadIdx.x & 63;
    if (v >= n) return;
    const float dv = dinv[v];

    float acc[CPL];
    {
        const uint* p = (const uint*)(h + (size_t)v * CH + lane * CPL);
        const float s2 = dv * dv;
#pragma unroll
        for (int j = 0; j < UPL; ++j) {
            const uint u = p[j];
            acc[2 * j]     = s2 * __uint_as_float(u << 16);
            acc[2 * j + 1] = s2 * __uint_as_float(u & 0xFFFF0000u);
        }
    }

    const int beg = row_ptr[v];
    const int end = row_ptr[v + 1];
    int i = beg;
    for (; i + 1 < end; i += 2) {  // 2-way ILP to overlap gather latency
        const int s0 = csr_src[i];
        const int s1 = csr_src[i + 1];
        const float n0 = dv * dinv[s0];
        const float n1 = dv * dinv[s1];
        const uint* p0 = (const uint*)(h + (size_t)s0 * CH + lane * CPL);
        const uint* p1 = (const uint*)(h + (size_t)s1 * CH + lane * CPL);
        uint u0[UPL], u1[UPL];
#pragma unroll
        for (int j = 0; j < UPL; ++j) { u0[j] = p0[j]; u1[j] = p1[j]; }
#pragma unroll
        for (int j = 0; j < UPL; ++j) {
            acc[2 * j]     = fmaf(n0, __uint_as_float(u0[j] << 16),
                             fmaf(n1, __uint_as_float(u1[j] << 16), acc[2 * j]));
            acc[2 * j + 1] = fmaf(n0, __uint_as_float(u0[j] & 0xFFFF0000u),
                             fmaf(n1, __uint_as_float(u1[j] & 0xFFFF0000u), acc[2 * j + 1]));
        }
    }
    if (i < end) {
        const int s0 = csr_src[i];
        const float n0 = dv * dinv[s0];
        const uint* p0 = (const uint*)(h + (size_t)s0 * CH + lane * CPL);
#pragma unroll
        for (int j = 0; j < UPL; ++j) {
            const uint u = p0[j];
            acc[2 * j]     = fmaf(n0, __uint_as_float(u << 16), acc[2 * j]);
            acc[2 * j + 1] = fmaf(n0, __uint_as_float(u & 0xFFFF0000u), acc[2 * j + 1]);
        }
    }

    uint o[UPL];
#pragma unroll
    for (int j = 0; j < UPL; ++j)
        o[j] = (unsigned)f2bf(acc[2 * j]) | ((unsigned)f2bf(acc[2 * j + 1]) << 16);
    uint* op = (uint*)(out + (size_t)v * CH + lane * CPL);
#pragma unroll
    for (int j = 0; j < UPL; ++j) op[j] = o[j];
}

// ---------------- MFMA GEMM + bias(+relu) epilogue: out[M,256] = A[M,K] @ W[K,256] + b ----------------
// Block = 4 waves, M-tile = 16. Wave w owns N-cols [64w, 64w+64) as 4x mfma_f32_16x16x32_bf16.
// A (bf16) staged in padded LDS; B from n-major bf16 Wt (L2-resident).
template <int K, bool RELU, typename OT>
__global__ __launch_bounds__(256) void k_gemm_mfma(const unsigned short* __restrict__ A,
                                                   const unsigned short* __restrict__ Wt,
                                                   const float* __restrict__ bias,
                                                   OT* __restrict__ out, int M) {
    constexpr int LDA = K + 8;  // +16B pad: breaks power-of-2 LDS stride
    __shared__ unsigned short sA[16 * LDA];
    const int t = threadIdx.x;
    const int row0 = blockIdx.x * 16;

    // stage 16 x K bf16 tile into LDS (16B chunks)
    {
        const int r = t >> 4;
        const int c0 = (t & 15) * (K / 16);
        const unsigned short* srcp = A + (size_t)(row0 + r) * K + c0;
        unsigned short* dstp = &sA[r * LDA + c0];
#pragma unroll
        for (int j = 0; j < K / 16; j += 8)
            *(uint4*)(dstp + j) = *(const uint4*)(srcp + j);
    }
    __syncthreads();

    const int wv = t >> 6;
    const int lane = t & 63;
    const int m16 = lane & 15;
    const int quad = lane >> 4;

    floatx4 acc0 = {0.f, 0.f, 0.f, 0.f};
    floatx4 acc1 = {0.f, 0.f, 0.f, 0.f};
    floatx4 acc2 = {0.f, 0.f, 0.f, 0.f};
    floatx4 acc3 = {0.f, 0.f, 0.f, 0.f};

    const unsigned short* ap = &sA[m16 * LDA + quad * 8];
    const unsigned short* bp = Wt + (size_t)(wv * 64 + m16) * K + quad * 8;

#pragma unroll
    for (int k0 = 0; k0 < K; k0 += 32) {
        const short8 a = *(const short8*)(ap + k0);
        const short8 b0 = *(const short8*)(bp + 0 * 16 * K + k0);
        const short8 b1 = *(const short8*)(bp + 1 * 16 * K + k0);
        const short8 b2 = *(const short8*)(bp + 2 * 16 * K + k0);
        const short8 b3 = *(const short8*)(bp + 3 * 16 * K + k0);
        acc0 = __builtin_amdgcn_mfma_f32_16x16x32_bf16(a, b0, acc0, 0, 0, 0);
        acc1 = __builtin_amdgcn_mfma_f32_16x16x32_bf16(a, b1, acc1, 0, 0, 0);
        acc2 = __builtin_amdgcn_mfma_f32_16x16x32_bf16(a, b2, acc2, 0, 0, 0);
        acc3 = __builtin_amdgcn_mfma_f32_16x16x32_bf16(a, b3, acc3, 0, 0, 0);
    }

    // D layout: col = lane&15, row = quad*4 + reg
    const int nbase = wv * 64 + m16;
    const float bb0 = bias[nbase + 0];
    const float bb1 = bias[nbase + 16];
    const float bb2 = bias[nbase + 32];
    const float bb3 = bias[nbase + 48];
#pragma unroll
    for (int j = 0; j < 4; ++j) {
        const size_t row = (size_t)(row0 + quad * 4 + j);
        float v0 = acc0[j] + bb0;
        float v1 = acc1[j] + bb1;
        float v2 = acc2[j] + bb2;
        float v3 = acc3[j] + bb3;
        if constexpr (RELU) {
            v0 = fmaxf(v0, 0.f); v1 = fmaxf(v1, 0.f);
            v2 = fmaxf(v2, 0.f); v3 = fmaxf(v3, 0.f);
        }
        if constexpr (sizeof(OT) == 4) {
            out[row * HID + nbase + 0]  = v0;
            out[row * HID + nbase + 16] = v1;
            out[row * HID + nbase + 32] = v2;
            out[row * HID + nbase + 48] = v3;
        } else {
            out[row * HID + nbase + 0]  = f2bf(v0);
            out[row * HID + nbase + 16] = f2bf(v1);
            out[row * HID + nbase + 32] = f2bf(v2);
            out[row * HID + nbase + 48] = f2bf(v3);
        }
    }
}

// ---------------- pool stage 1: chunked partial sums (relu fused) ----------------
#define POOL_CHUNK 64
__global__ __launch_bounds__(256) void k_pool_partial(const float* __restrict__ h,
                                                      const int* __restrict__ batch,
                                                      float* __restrict__ pooled_sum, int n) {
    const int c = threadIdx.x;  // 256
    const int v0 = blockIdx.x * POOL_CHUNK;
    const int v1 = min(v0 + POOL_CHUNK, n);
    if (v0 >= n) return;
    int cur_g = batch[v0];
    float sum = 0.0f;
    for (int v = v0; v < v1; ++v) {
        const int g = batch[v];            // block-uniform
        const float val = fmaxf(h[(size_t)v * HID + c], 0.0f);
        if (g != cur_g) {                  // uniform branch
            atomicAdd(&pooled_sum[cur_g * HID + c], sum);
            sum = 0.0f;
            cur_g = g;
        }
        sum += val;
    }
    atomicAdd(&pooled_sum[cur_g * HID + c], sum);
}

// ---------------- final FC with fused mean: out[g] = (sum[g] @ Wfc)/cnt + bfc ----------------
__global__ void k_fc(const float* __restrict__ pooled_sum, const int* __restrict__ batch,
                     const float* __restrict__ W, const float* __restrict__ b,
                     float* __restrict__ out, int n) {
    const int g = blockIdx.x;
    const int c = threadIdx.x;  // 128
    int a = 0, hi = n;
    while (a < hi) { int m = (a + hi) >> 1; if (batch[m] < g) a = m + 1; else hi = m; }
    const int start = a;
    hi = n;
    while (a < hi) { int m = (a + hi) >> 1; if (batch[m] < g + 1) a = m + 1; else hi = m; }
    const float cnt = (float)(a - start);

    float acc = 0.0f;
    const float* p = pooled_sum + g * HID;
    for (int k = 0; k < HID; ++k) acc += p[k] * W[k * OUTC + c];
    out[g * OUTC + c] = acc / fmaxf(cnt, 1.0f) + b[c];
}

extern "C" void kernel_launch(void* const* d_in, const int* in_sizes, int n_in,
                              void* d_out, int out_size, void* d_ws, size_t ws_size,
                              hipStream_t stream) {
    const float* x   = (const float*)d_in[0];
    const int*   ei  = (const int*)d_in[1];
    const int*   bat = (const int*)d_in[2];
    const float* W1  = (const float*)d_in[3];
    const float* b1  = (const float*)d_in[4];
    const float* W2  = (const float*)d_in[5];
    const float* b2  = (const float*)d_in[6];
    const float* Wfc = (const float*)d_in[7];
    const float* bfc = (const float*)d_in[8];
    float* out = (float*)d_out;

    const int n = in_sizes[2];       // 50000 nodes (divisible by 16)
    const int e = in_sizes[1] / 2;   // 800000 edges
    const int* src = ei;
    const int* dst = ei + e;
    const int nb = (n + 255) / 256;  // scan blocks (<=256 required; 196 here)

    // Workspace layout
    char* wsb = (char*)d_ws;
    int*   cnt     = (int*)wsb;                        wsb += (size_t)n * 4;
    int*   row_ptr = (int*)wsb;                        wsb += (size_t)(n + 1) * 4;
    int*   blk_sum = (int*)wsb;                        wsb += (size_t)512 * 4;
    int*   csr_src = (int*)wsb;                        wsb += (size_t)e * 4;
    float* dinv    = (float*)wsb;                      wsb += (size_t)n * 4;
    unsigned short* Wt1 = (unsigned short*)wsb;        wsb += (size_t)INC * HID * 2;
    unsigned short* Wt2 = (unsigned short*)wsb;        wsb += (size_t)HID * HID * 2;
    unsigned short* R1  = (unsigned short*)wsb;        wsb += (size_t)n * HID * 2;  // xbf, later agg1
    unsigned short* R2  = (unsigned short*)wsb;        wsb += (size_t)n * INC * 2;  // agg0
    unsigned short* R3  = (unsigned short*)wsb;        wsb += (size_t)n * HID * 2;  // h1
    float* out2   = (float*)wsb;                       wsb += (size_t)n * HID * 4;  // conv2 out (fp32)
    float* pooled = (float*)wsb;                       // 128*256 fp32 sums

    const int TB = 256;
    hipMemsetAsync(cnt, 0, (size_t)n * 4, stream);
    hipMemsetAsync(pooled, 0, (size_t)128 * HID * 4, stream);

    // x -> bf16
    k_convX<<<((n * INC / 4) + TB - 1) / TB, TB, 0, stream>>>(x, R1, n * INC / 4);

    // CSR build
    k_hist<<<(e + TB - 1) / TB, TB, 0, stream>>>(dst, cnt, e);
    k_dinv<<<(n + TB - 1) / TB, TB, 0, stream>>>(cnt, dinv, n);
    k_scan_local<<<nb, TB, 0, stream>>>(cnt, row_ptr, blk_sum, n);
    k_scan_blk<<<1, TB, 0, stream>>>(blk_sum, nb);
    k_scan_add<<<nb, TB, 0, stream>>>(row_ptr, blk_sum, cnt, n, e);
    k_fill<<<(e + TB - 1) / TB, TB, 0, stream>>>(src, dst, row_ptr, cnt, csr_src, e);

    // Weight transpose + bf16 convert
    k_convW<<<INC, TB, 0, stream>>>(W1, Wt1, INC);
    k_convW<<<HID, TB, 0, stream>>>(W2, Wt2, HID);

    const int gemm_blocks = n / 16;
    const int agg_blocks = (n + 3) / 4;

    // Layer 1 (reordered via linearity): agg0 = A.x ; h1 = relu(agg0 @ W1 + b1)
    k_agg<INC><<<agg_blocks, TB, 0, stream>>>(R1, row_ptr, csr_src, dinv, R2, n);
    k_gemm_mfma<INC, true, unsigned short><<<gemm_blocks, TB, 0, stream>>>(R2, Wt1, b1, R3, n);

    // Layer 2: agg1 = A.h1 ; out2 = agg1 @ W2 + b2 (fp32, relu deferred to pool)
    k_agg<HID><<<agg_blocks, TB, 0, stream>>>(R3, row_ptr, csr_src, dinv, R1, n);
    k_gemm_mfma<HID, false, float><<<gemm_blocks, TB, 0, stream>>>(R1, Wt2, b2, out2, n);

    // Pool (relu + mean fused) + FC
    k_pool_partial<<<(n + POOL_CHUNK - 1) / POOL_CHUNK, TB, 0, stream>>>(out2, bat, pooled, n);
    k_fc<<<128, 128, 0, stream>>>(pooled, bat, Wfc, bfc, out, n);
}

// Round 8
// 360.545 us; speedup vs baseline: 16.1853x; 1.2155x over previous
//
#include <hip/hip_runtime.h>
#include <type_traits>

// Problem constants (fixed by the reference)
#define HID 256
#define INC 128
#define OUTC 128

typedef __attribute__((ext_vector_type(8))) short short8;     // 8 bf16 = 4 VGPRs (MFMA A/B frag)
typedef __attribute__((ext_vector_type(4))) float floatx4;    // MFMA C/D frag

__device__ __forceinline__ unsigned short f2bf(float f) {
    unsigned int u = __float_as_uint(f);
    unsigned int r = (u + 0x7FFFu + ((u >> 16) & 1u)) >> 16;  // RNE
    return (unsigned short)r;
}

__device__ __forceinline__ void bfacc2(float* a, uint u, float nr) {
    a[0] = fmaf(nr, __uint_as_float(u << 16), a[0]);
    a[1] = fmaf(nr, __uint_as_float(u & 0xFFFF0000u), a[1]);
}

// ---------------- x -> bf16 convert ----------------
__global__ void k_convX(const float* __restrict__ x, unsigned short* __restrict__ xb, int total4) {
    int i = blockIdx.x * 256 + threadIdx.x;
    if (i < total4) {
        const float4 v = *(const float4*)(x + (size_t)i * 4);
        uint2 o;
        o.x = (unsigned)f2bf(v.x) | ((unsigned)f2bf(v.y) << 16);
        o.y = (unsigned)f2bf(v.z) | ((unsigned)f2bf(v.w) << 16);
        *(uint2*)(xb + (size_t)i * 4) = o;
    }
}

// ---------------- CSR build ----------------
__global__ void k_hist(const int* __restrict__ dst, int* __restrict__ cnt, int e) {
    int i = blockIdx.x * blockDim.x + threadIdx.x;
    if (i < e) atomicAdd(&cnt[dst[i]], 1);
}

// Local scan (per 256-block) + dinv computed from pre-scan counts (fused).
__global__ __launch_bounds__(256) void k_scan_local(const int* __restrict__ cnt,
                                                    int* __restrict__ ex, int* __restrict__ blk_sum,
                                                    float* __restrict__ dinv, int n) {
    __shared__ int s[256];
    const int t = threadIdx.x;
    const int i = blockIdx.x * 256 + t;
    const int v = (i < n) ? cnt[i] : 0;
    if (i < n) dinv[i] = rsqrtf((float)v + 1.0f);  // +1 self loop
    s[t] = v;
    __syncthreads();
    for (int off = 1; off < 256; off <<= 1) {
        int add = (t >= off) ? s[t - off] : 0;
        __syncthreads();
        s[t] += add;
        __syncthreads();
    }
    if (i < n) ex[i] = s[t] - v;
    if (t == 255) blk_sum[blockIdx.x] = s[255];
}

__global__ __launch_bounds__(256) void k_scan_blk(int* __restrict__ blk_sum, int nb) {
    __shared__ int s[256];
    const int t = threadIdx.x;
    const int v = (t < nb) ? blk_sum[t] : 0;
    s[t] = v;
    __syncthreads();
    for (int off = 1; off < 256; off <<= 1) {
        int add = (t >= off) ? s[t - off] : 0;
        __syncthreads();
        s[t] += add;
        __syncthreads();
    }
    if (t < nb) blk_sum[t] = s[t] - v;  // exclusive
}

__global__ void k_scan_add(int* __restrict__ row_ptr, const int* __restrict__ blk_sum,
                           int* __restrict__ cnt, int n, int e) {
    int i = blockIdx.x * 256 + threadIdx.x;
    if (i < n) { row_ptr[i] += blk_sum[i >> 8]; cnt[i] = 0; }  // cnt reset -> fill cursor
    if (i == 0) row_ptr[n] = e;
}

__global__ void k_fill(const int* __restrict__ src, const int* __restrict__ dst,
                       const int* __restrict__ row_ptr, int* __restrict__ cursor,
                       int* __restrict__ csr_src, int e) {
    int i = blockIdx.x * blockDim.x + threadIdx.x;
    if (i < e) {
        const int d = dst[i];
        const int pos = row_ptr[d] + atomicAdd(&cursor[d], 1);
        csr_src[pos] = src[i];
    }
}

// ---------------- W transpose + bf16 convert: Wt[n][k] = bf16(W[k][n]) ----------------
__global__ void k_convW(const float* __restrict__ W, unsigned short* __restrict__ Wt, int K) {
    int id = blockIdx.x * 256 + threadIdx.x;  // id = n*K + k
    if (id < K * HID) {
        int n = id / K;
        int k = id - n * K;
        Wt[id] = f2bf(W[k * HID + n]);
    }
}

// ---------------- pull-mode aggregation: out = A_norm . h (no atomics, no bias) ----------------
// One wave per node v: out[v] = dinv[v]^2*h[v] + sum_in dinv[s]*dinv[v]*h[s]
// 4-edge ILP: 4 row-gathers in flight per wave. CH=128 -> uint/lane, CH=256 -> uint2/lane.
template <int CH>
__global__ __launch_bounds__(256) void k_agg(const unsigned short* __restrict__ h,
                                             const int* __restrict__ row_ptr,
                                             const int* __restrict__ csr_src,
                                             const float* __restrict__ dinv,
                                             unsigned short* __restrict__ out, int n) {
    constexpr int CPL = CH / 64;  // bf16 per lane: 2 or 4
    using VT = std::conditional_t<CPL == 2, uint, uint2>;
    const int v = (blockIdx.x * 256 + threadIdx.x) >> 6;
    const int lane = threadIdx.x & 63;
    if (v >= n) return;
    const float dv = dinv[v];
    const unsigned short* hl = h + lane * CPL;

    float acc[CPL];
    {
        const VT u = *(const VT*)(hl + (size_t)v * CH);
        const float s2 = dv * dv;
        if constexpr (CPL == 2) {
            acc[0] = s2 * __uint_as_float(((uint)u) << 16);
            acc[1] = s2 * __uint_as_float(((uint)u) & 0xFFFF0000u);
        } else {
            const uint2 w = (uint2)u;
            acc[0] = s2 * __uint_as_float(w.x << 16);
            acc[1] = s2 * __uint_as_float(w.x & 0xFFFF0000u);
            acc[2] = s2 * __uint_as_float(w.y << 16);
            acc[3] = s2 * __uint_as_float(w.y & 0xFFFF0000u);
        }
    }

    const int beg = row_ptr[v];
    const int end = row_ptr[v + 1];
    int i = beg;
    for (; i + 4 <= end; i += 4) {  // 4 gathers in flight
        const int s0 = csr_src[i];
        const int s1 = csr_src[i + 1];
        const int s2i = csr_src[i + 2];
        const int s3 = csr_src[i + 3];
        const float n0 = dv * dinv[s0];
        const float n1 = dv * dinv[s1];
        const float n2 = dv * dinv[s2i];
        const float n3 = dv * dinv[s3];
        const VT r0 = *(const VT*)(hl + (size_t)s0 * CH);
        const VT r1 = *(const VT*)(hl + (size_t)s1 * CH);
        const VT r2 = *(const VT*)(hl + (size_t)s2i * CH);
        const VT r3 = *(const VT*)(hl + (size_t)s3 * CH);
        if constexpr (CPL == 2) {
            bfacc2(acc, (uint)r0, n0);
            bfacc2(acc, (uint)r1, n1);
            bfacc2(acc, (uint)r2, n2);
            bfacc2(acc, (uint)r3, n3);
        } else {
            const uint2 w0 = (uint2)r0, w1 = (uint2)r1, w2 = (uint2)r2, w3 = (uint2)r3;
            bfacc2(acc, w0.x, n0); bfacc2(acc + 2, w0.y, n0);
            bfacc2(acc, w1.x, n1); bfacc2(acc + 2, w1.y, n1);
            bfacc2(acc, w2.x, n2); bfacc2(acc + 2, w2.y, n2);
            bfacc2(acc, w3.x, n3); bfacc2(acc + 2, w3.y, n3);
        }
    }
    for (; i < end; ++i) {
        const int s0 = csr_src[i];
        const float n0 = dv * dinv[s0];
        const VT r0 = *(const VT*)(hl + (size_t)s0 * CH);
        if constexpr (CPL == 2) {
            bfacc2(acc, (uint)r0, n0);
        } else {
            const uint2 w0 = (uint2)r0;
            bfacc2(acc, w0.x, n0); bfacc2(acc + 2, w0.y, n0);
        }
    }

    if constexpr (CPL == 2) {
        uint o = (unsigned)f2bf(acc[0]) | ((unsigned)f2bf(acc[1]) << 16);
        *(uint*)(out + (size_t)v * CH + lane * CPL) = o;
    } else {
        uint2 o;
        o.x = (unsigned)f2bf(acc[0]) | ((unsigned)f2bf(acc[1]) << 16);
        o.y = (unsigned)f2bf(acc[2]) | ((unsigned)f2bf(acc[3]) << 16);
        *(uint2*)(out + (size_t)v * CH + lane * CPL) = o;
    }
}

// ---------------- MFMA GEMM + bias(+relu): out[M,256] = A[M,K] @ W[K,256] + b ----------------
// Block = 4 waves, M-tile = 32 (2 row-subtiles of 16). Wave w owns N-cols [64w, 64w+64)
// as 2x4 mfma_f32_16x16x32_bf16. A (bf16) in padded LDS; B from n-major bf16 Wt (L2).
template <int K, bool RELU, typename OT>
__global__ __launch_bounds__(256) void k_gemm_mfma(const unsigned short* __restrict__ A,
                                                   const unsigned short* __restrict__ Wt,
                                                   const float* __restrict__ bias,
                                                   OT* __restrict__ out, int M) {
    constexpr int LDA = K + 8;  // +16B pad: breaks power-of-2 LDS stride
    __shared__ unsigned short sA[32 * LDA];
    const int t = threadIdx.x;
    const int row0 = blockIdx.x * 32;

    // stage 32 x K bf16 tile into LDS (16B chunks); zero-fill rows >= M
    {
        const int r = t >> 3;                // 0..31
        const int c0 = (t & 7) * (K / 8);    // K=128 -> 16 cols, K=256 -> 32 cols
        unsigned short* dstp = &sA[r * LDA + c0];
        if (row0 + r < M) {
            const unsigned short* srcp = A + (size_t)(row0 + r) * K + c0;
#pragma unroll
            for (int j = 0; j < K / 8; j += 8)
                *(uint4*)(dstp + j) = *(const uint4*)(srcp + j);
        } else {
            const uint4 z = {0, 0, 0, 0};
#pragma unroll
            for (int j = 0; j < K / 8; j += 8) *(uint4*)(dstp + j) = z;
        }
    }
    __syncthreads();

    const int wv = t >> 6;
    const int lane = t & 63;
    const int m16 = lane & 15;
    const int quad = lane >> 4;

    floatx4 acc[2][4];
#pragma unroll
    for (int h2 = 0; h2 < 2; ++h2)
#pragma unroll
        for (int j = 0; j < 4; ++j) acc[h2][j] = (floatx4){0.f, 0.f, 0.f, 0.f};

    const unsigned short* ap0 = &sA[m16 * LDA + quad * 8];
    const unsigned short* ap1 = &sA[(16 + m16) * LDA + quad * 8];
    const unsigned short* bp = Wt + (size_t)(wv * 64 + m16) * K + quad * 8;

#pragma unroll
    for (int k0 = 0; k0 < K; k0 += 32) {
        const short8 a0 = *(const short8*)(ap0 + k0);
        const short8 a1 = *(const short8*)(ap1 + k0);
        const short8 b0 = *(const short8*)(bp + 0 * 16 * K + k0);
        const short8 b1 = *(const short8*)(bp + 1 * 16 * K + k0);
        const short8 b2 = *(const short8*)(bp + 2 * 16 * K + k0);
        const short8 b3 = *(const short8*)(bp + 3 * 16 * K + k0);
        acc[0][0] = __builtin_amdgcn_mfma_f32_16x16x32_bf16(a0, b0, acc[0][0], 0, 0, 0);
        acc[0][1] = __builtin_amdgcn_mfma_f32_16x16x32_bf16(a0, b1, acc[0][1], 0, 0, 0);
        acc[0][2] = __builtin_amdgcn_mfma_f32_16x16x32_bf16(a0, b2, acc[0][2], 0, 0, 0);
        acc[0][3] = __builtin_amdgcn_mfma_f32_16x16x32_bf16(a0, b3, acc[0][3], 0, 0, 0);
        acc[1][0] = __builtin_amdgcn_mfma_f32_16x16x32_bf16(a1, b0, acc[1][0], 0, 0, 0);
        acc[1][1] = __builtin_amdgcn_mfma_f32_16x16x32_bf16(a1, b1, acc[1][1], 0, 0, 0);
        acc[1][2] = __builtin_amdgcn_mfma_f32_16x16x32_bf16(a1, b2, acc[1][2], 0, 0, 0);
        acc[1][3] = __builtin_amdgcn_mfma_f32_16x16x32_bf16(a1, b3, acc[1][3], 0, 0, 0);
    }

    // D layout: col = lane&15 (N), row = quad*4 + reg (M within subtile)
    const int nbase = wv * 64 + m16;
    const float bb0 = bias[nbase + 0];
    const float bb1 = bias[nbase + 16];
    const float bb2 = bias[nbase + 32];
    const float bb3 = bias[nbase + 48];
#pragma unroll
    for (int h2 = 0; h2 < 2; ++h2) {
#pragma unroll
        for (int j = 0; j < 4; ++j) {
            const int row = row0 + h2 * 16 + quad * 4 + j;
            if (row >= M) continue;
            float v0 = acc[h2][0][j] + bb0;
            float v1 = acc[h2][1][j] + bb1;
            float v2 = acc[h2][2][j] + bb2;
            float v3 = acc[h2][3][j] + bb3;
            if constexpr (RELU) {
                v0 = fmaxf(v0, 0.f); v1 = fmaxf(v1, 0.f);
                v2 = fmaxf(v2, 0.f); v3 = fmaxf(v3, 0.f);
            }
            if constexpr (sizeof(OT) == 4) {
                out[(size_t)row * HID + nbase + 0]  = v0;
                out[(size_t)row * HID + nbase + 16] = v1;
                out[(size_t)row * HID + nbase + 32] = v2;
                out[(size_t)row * HID + nbase + 48] = v3;
            } else {
                out[(size_t)row * HID + nbase + 0]  = f2bf(v0);
                out[(size_t)row * HID + nbase + 16] = f2bf(v1);
                out[(size_t)row * HID + nbase + 32] = f2bf(v2);
                out[(size_t)row * HID + nbase + 48] = f2bf(v3);
            }
        }
    }
}

// ---------------- pool stage 1: chunked partial sums (relu fused) ----------------
#define POOL_CHUNK 64
__global__ __launch_bounds__(256) void k_pool_partial(const float* __restrict__ h,
                                                      const int* __restrict__ batch,
                                                      float* __restrict__ pooled_sum, int n) {
    const int c = threadIdx.x;  // 256
    const int v0 = blockIdx.x * POOL_CHUNK;
    const int v1 = min(v0 + POOL_CHUNK, n);
    if (v0 >= n) return;
    int cur_g = batch[v0];
    float sum = 0.0f;
    for (int v = v0; v < v1; ++v) {
        const int g = batch[v];            // block-uniform
        const float val = fmaxf(h[(size_t)v * HID + c], 0.0f);
        if (g != cur_g) {                  // uniform branch
            atomicAdd(&pooled_sum[cur_g * HID + c], sum);
            sum = 0.0f;
            cur_g = g;
        }
        sum += val;
    }
    atomicAdd(&pooled_sum[cur_g * HID + c], sum);
}

// ---------------- final FC with fused mean: out[g] = (sum[g] @ Wfc)/cnt + bfc ----------------
__global__ void k_fc(const float* __restrict__ pooled_sum, const int* __restrict__ batch,
                     const float* __restrict__ W, const float* __restrict__ b,
                     float* __restrict__ out, int n) {
    const int g = blockIdx.x;
    const int c = threadIdx.x;  // 128
    int a = 0, hi = n;
    while (a < hi) { int m = (a + hi) >> 1; if (batch[m] < g) a = m + 1; else hi = m; }
    const int start = a;
    hi = n;
    while (a < hi) { int m = (a + hi) >> 1; if (batch[m] < g + 1) a = m + 1; else hi = m; }
    const float cnt = (float)(a - start);

    float acc = 0.0f;
    const float* p = pooled_sum + g * HID;
    for (int k = 0; k < HID; ++k) acc += p[k] * W[k * OUTC + c];
    out[g * OUTC + c] = acc / fmaxf(cnt, 1.0f) + b[c];
}

extern "C" void kernel_launch(void* const* d_in, const int* in_sizes, int n_in,
                              void* d_out, int out_size, void* d_ws, size_t ws_size,
                              hipStream_t stream) {
    const float* x   = (const float*)d_in[0];
    const int*   ei  = (const int*)d_in[1];
    const int*   bat = (const int*)d_in[2];
    const float* W1  = (const float*)d_in[3];
    const float* b1  = (const float*)d_in[4];
    const float* W2  = (const float*)d_in[5];
    const float* b2  = (const float*)d_in[6];
    const float* Wfc = (const float*)d_in[7];
    const float* bfc = (const float*)d_in[8];
    float* out = (float*)d_out;

    const int n = in_sizes[2];       // 50000 nodes
    const int e = in_sizes[1] / 2;   // 800000 edges
    const int* src = ei;
    const int* dst = ei + e;
    const int nb = (n + 255) / 256;  // scan blocks (196 <= 256)

    // Workspace layout (each buffer 256B-aligned)
    size_t off = 0;
    auto alloc = [&](size_t bytes) {
        char* p = (char*)d_ws + off;
        off += (bytes + 255) & ~(size_t)255;
        return p;
    };
    int*   cnt     = (int*)alloc((size_t)n * 4);
    int*   row_ptr = (int*)alloc((size_t)(n + 1) * 4);
    int*   blk_sum = (int*)alloc(512 * 4);
    int*   csr_src = (int*)alloc((size_t)e * 4);
    float* dinv    = (float*)alloc((size_t)n * 4);
    unsigned short* Wt1 = (unsigned short*)alloc((size_t)INC * HID * 2);
    unsigned short* Wt2 = (unsigned short*)alloc((size_t)HID * HID * 2);
    unsigned short* R1  = (unsigned short*)alloc((size_t)n * HID * 2);  // xbf, later agg1
    unsigned short* R2  = (unsigned short*)alloc((size_t)n * INC * 2);  // agg0
    unsigned short* R3  = (unsigned short*)alloc((size_t)n * HID * 2);  // h1
    float* out2   = (float*)alloc((size_t)n * HID * 4);                 // conv2 out (fp32)
    float* pooled = (float*)alloc((size_t)128 * HID * 4);               // fp32 sums

    const int TB = 256;
    hipMemsetAsync(cnt, 0, (size_t)n * 4, stream);
    hipMemsetAsync(pooled, 0, (size_t)128 * HID * 4, stream);

    // x -> bf16
    k_convX<<<((n * INC / 4) + TB - 1) / TB, TB, 0, stream>>>(x, R1, n * INC / 4);

    // CSR build (dinv fused into scan_local)
    k_hist<<<(e + TB - 1) / TB, TB, 0, stream>>>(dst, cnt, e);
    k_scan_local<<<nb, TB, 0, stream>>>(cnt, row_ptr, blk_sum, dinv, n);
    k_scan_blk<<<1, TB, 0, stream>>>(blk_sum, nb);
    k_scan_add<<<nb, TB, 0, stream>>>(row_ptr, blk_sum, cnt, n, e);
    k_fill<<<(e + TB - 1) / TB, TB, 0, stream>>>(src, dst, row_ptr, cnt, csr_src, e);

    // Weight transpose + bf16 convert
    k_convW<<<INC, TB, 0, stream>>>(W1, Wt1, INC);
    k_convW<<<HID, TB, 0, stream>>>(W2, Wt2, HID);

    const int gemm_blocks = (n + 31) / 32;
    const int agg_blocks = (n + 3) / 4;

    // Layer 1 (reordered via linearity): agg0 = A.x ; h1 = relu(agg0 @ W1 + b1)
    k_agg<INC><<<agg_blocks, TB, 0, stream>>>(R1, row_ptr, csr_src, dinv, R2, n);
    k_gemm_mfma<INC, true, unsigned short><<<gemm_blocks, TB, 0, stream>>>(R2, Wt1, b1, R3, n);

    // Layer 2: agg1 = A.h1 ; out2 = agg1 @ W2 + b2 (fp32, relu deferred to pool)
    k_agg<HID><<<agg_blocks, TB, 0, stream>>>(R3, row_ptr, csr_src, dinv, R1, n);
    k_gemm_mfma<HID, false, float><<<gemm_blocks, TB, 0, stream>>>(R1, Wt2, b2, out2, n);

    // Pool (relu + mean fused) + FC
    k_pool_partial<<<(n + POOL_CHUNK - 1) / POOL_CHUNK, TB, 0, stream>>>(out2, bat, pooled, n);
    k_fc<<<128, 128, 0, stream>>>(pooled, bat, Wfc, bfc, out, n);
}

// Round 9
// 358.483 us; speedup vs baseline: 16.2784x; 1.0058x over previous
//
#include <hip/hip_runtime.h>
#include <type_traits>

// Problem constants (fixed by the reference)
#define HID 256
#define INC 128
#define OUTC 128

typedef __attribute__((ext_vector_type(8))) short short8;     // 8 bf16 = 4 VGPRs (MFMA A/B frag)
typedef __attribute__((ext_vector_type(4))) float floatx4;    // MFMA C/D frag

__device__ __forceinline__ unsigned short f2bf(float f) {
    unsigned int u = __float_as_uint(f);
    unsigned int r = (u + 0x7FFFu + ((u >> 16) & 1u)) >> 16;  // RNE
    return (unsigned short)r;
}

__device__ __forceinline__ void bfacc2(float* a, uint u, float nr) {
    a[0] = fmaf(nr, __uint_as_float(u << 16), a[0]);
    a[1] = fmaf(nr, __uint_as_float(u & 0xFFFF0000u), a[1]);
}

// ---------------- x -> bf16 convert ----------------
__global__ void k_convX(const float* __restrict__ x, unsigned short* __restrict__ xb, int total4) {
    int i = blockIdx.x * 256 + threadIdx.x;
    if (i < total4) {
        const float4 v = *(const float4*)(x + (size_t)i * 4);
        uint2 o;
        o.x = (unsigned)f2bf(v.x) | ((unsigned)f2bf(v.y) << 16);
        o.y = (unsigned)f2bf(v.z) | ((unsigned)f2bf(v.w) << 16);
        *(uint2*)(xb + (size_t)i * 4) = o;
    }
}

// ---------------- CSR build ----------------
__global__ void k_hist(const int* __restrict__ dst, int* __restrict__ cnt, int e) {
    int i = blockIdx.x * blockDim.x + threadIdx.x;
    if (i < e) atomicAdd(&cnt[dst[i]], 1);
}

// Local scan (per 256-block) + dinv computed from pre-scan counts (fused).
__global__ __launch_bounds__(256) void k_scan_local(const int* __restrict__ cnt,
                                                    int* __restrict__ ex, int* __restrict__ blk_sum,
                                                    float* __restrict__ dinv, int n) {
    __shared__ int s[256];
    const int t = threadIdx.x;
    const int i = blockIdx.x * 256 + t;
    const int v = (i < n) ? cnt[i] : 0;
    if (i < n) dinv[i] = rsqrtf((float)v + 1.0f);  // +1 self loop
    s[t] = v;
    __syncthreads();
    for (int off = 1; off < 256; off <<= 1) {
        int add = (t >= off) ? s[t - off] : 0;
        __syncthreads();
        s[t] += add;
        __syncthreads();
    }
    if (i < n) ex[i] = s[t] - v;
    if (t == 255) blk_sum[blockIdx.x] = s[255];
}

// Adds global block offset (computed by block-local reduction of blk_sum) + resets cnt.
__global__ __launch_bounds__(256) void k_scan_add(int* __restrict__ row_ptr,
                                                  const int* __restrict__ blk_sum,
                                                  int* __restrict__ cnt, int n, int e) {
    __shared__ int s[256];
    const int t = threadIdx.x;
    const int b = blockIdx.x;
    s[t] = (t < b) ? blk_sum[t] : 0;   // nb <= 256 guaranteed (n <= 65536)
    __syncthreads();
    for (int off = 128; off > 0; off >>= 1) {
        if (t < off) s[t] += s[t + off];
        __syncthreads();
    }
    const int offset = s[0];
    const int i = b * 256 + t;
    if (i < n) { row_ptr[i] += offset; cnt[i] = 0; }  // cnt reset -> fill cursor
    if (i == 0) row_ptr[n] = e;
}

__global__ void k_fill(const int* __restrict__ src, const int* __restrict__ dst,
                       const int* __restrict__ row_ptr, int* __restrict__ cursor,
                       int* __restrict__ csr_src, int e) {
    int i = blockIdx.x * blockDim.x + threadIdx.x;
    if (i < e) {
        const int d = dst[i];
        const int pos = row_ptr[d] + atomicAdd(&cursor[d], 1);
        csr_src[pos] = src[i];
    }
}

// ---------------- both W transposes + bf16 convert in one dispatch ----------------
// Wt[n][k] = bf16(W[k][n]); ids [0, INC*HID) -> W1, [INC*HID, INC*HID+HID*HID) -> W2.
__global__ void k_convW(const float* __restrict__ W1, unsigned short* __restrict__ Wt1,
                        const float* __restrict__ W2, unsigned short* __restrict__ Wt2) {
    int id = blockIdx.x * 256 + threadIdx.x;
    if (id < INC * HID) {
        int n = id / INC;
        int k = id - n * INC;
        Wt1[id] = f2bf(W1[k * HID + n]);
    } else if (id < INC * HID + HID * HID) {
        int id2 = id - INC * HID;
        int n = id2 / HID;
        int k = id2 - n * HID;
        Wt2[id2] = f2bf(W2[k * HID + n]);
    }
}

// ---------------- pull-mode aggregation: out = A_norm . h (no atomics, no bias) ----------------
// One wave per node v: out[v] = dinv[v]^2*h[v] + sum_in dinv[s]*dinv[v]*h[s]
// 8-edge ILP: 8 row-gathers in flight per wave. CH=128 -> uint/lane, CH=256 -> uint2/lane.
template <int CH>
__global__ __launch_bounds__(256) void k_agg(const unsigned short* __restrict__ h,
                                             const int* __restrict__ row_ptr,
                                             const int* __restrict__ csr_src,
                                             const float* __restrict__ dinv,
                                             unsigned short* __restrict__ out, int n) {
    constexpr int CPL = CH / 64;  // bf16 per lane: 2 or 4
    using VT = std::conditional_t<CPL == 2, uint, uint2>;
    const int v = (blockIdx.x * 256 + threadIdx.x) >> 6;
    const int lane = threadIdx.x & 63;
    if (v >= n) return;
    const float dv = dinv[v];
    const unsigned short* hl = h + lane * CPL;

    float acc[CPL];
    {
        const VT u = *(const VT*)(hl + (size_t)v * CH);
        const float s2 = dv * dv;
        if constexpr (CPL == 2) {
            acc[0] = s2 * __uint_as_float(((uint)u) << 16);
            acc[1] = s2 * __uint_as_float(((uint)u) & 0xFFFF0000u);
        } else {
            const uint2 w = (uint2)u;
            acc[0] = s2 * __uint_as_float(w.x << 16);
            acc[1] = s2 * __uint_as_float(w.x & 0xFFFF0000u);
            acc[2] = s2 * __uint_as_float(w.y << 16);
            acc[3] = s2 * __uint_as_float(w.y & 0xFFFF0000u);
        }
    }

    const int beg = row_ptr[v];
    const int end = row_ptr[v + 1];
    int i = beg;
    for (; i + 8 <= end; i += 8) {  // 8 gathers in flight
        int si[8];
        float nr[8];
        VT r[8];
#pragma unroll
        for (int j = 0; j < 8; ++j) si[j] = csr_src[i + j];
#pragma unroll
        for (int j = 0; j < 8; ++j) nr[j] = dv * dinv[si[j]];
#pragma unroll
        for (int j = 0; j < 8; ++j) r[j] = *(const VT*)(hl + (size_t)si[j] * CH);
#pragma unroll
        for (int j = 0; j < 8; ++j) {
            if constexpr (CPL == 2) {
                bfacc2(acc, (uint)r[j], nr[j]);
            } else {
                const uint2 w = (uint2)r[j];
                bfacc2(acc, w.x, nr[j]);
                bfacc2(acc + 2, w.y, nr[j]);
            }
        }
    }
    for (; i < end; ++i) {
        const int s0 = csr_src[i];
        const float n0 = dv * dinv[s0];
        const VT r0 = *(const VT*)(hl + (size_t)s0 * CH);
        if constexpr (CPL == 2) {
            bfacc2(acc, (uint)r0, n0);
        } else {
            const uint2 w0 = (uint2)r0;
            bfacc2(acc, w0.x, n0); bfacc2(acc + 2, w0.y, n0);
        }
    }

    if constexpr (CPL == 2) {
        uint o = (unsigned)f2bf(acc[0]) | ((unsigned)f2bf(acc[1]) << 16);
        *(uint*)(out + (size_t)v * CH + lane * CPL) = o;
    } else {
        uint2 o;
        o.x = (unsigned)f2bf(acc[0]) | ((unsigned)f2bf(acc[1]) << 16);
        o.y = (unsigned)f2bf(acc[2]) | ((unsigned)f2bf(acc[3]) << 16);
        *(uint2*)(out + (size_t)v * CH + lane * CPL) = o;
    }
}

// ---------------- MFMA GEMM: out = A[M,K] @ W[K,256] + b, with optional fused relu+pool ----------------
// Block = 4 waves, M-tile = 32. Wave w owns N-cols [64w, 64w+64) as 2x4 mfma_f32_16x16x32_bf16.
// POOL: no global store of the result; relu'd values are segment-summed over the block's rows
// (batch sorted -> few segments) and atomicAdd'ed into pooled_sum[128][256] (L2-resident).
template <int K, bool RELU, bool POOL, typename OT>
__global__ __launch_bounds__(256) void k_gemm_mfma(const unsigned short* __restrict__ A,
                                                   const unsigned short* __restrict__ Wt,
                                                   const float* __restrict__ bias,
                                                   OT* __restrict__ out,
                                                   const int* __restrict__ batch,
                                                   float* __restrict__ pooled_sum, int M) {
    constexpr int LDA = K + 8;  // +16B pad: breaks power-of-2 LDS stride
    __shared__ unsigned short sA[32 * LDA];
    __shared__ int s_batch[32];
    const int t = threadIdx.x;
    const int row0 = blockIdx.x * 32;

    // stage 32 x K bf16 tile into LDS (16B chunks); zero-fill rows >= M
    {
        const int r = t >> 3;                // 0..31
        const int c0 = (t & 7) * (K / 8);    // K=128 -> 16 cols, K=256 -> 32 cols
        unsigned short* dstp = &sA[r * LDA + c0];
        if (row0 + r < M) {
            const unsigned short* srcp = A + (size_t)(row0 + r) * K + c0;
#pragma unroll
            for (int j = 0; j < K / 8; j += 8)
                *(uint4*)(dstp + j) = *(const uint4*)(srcp + j);
        } else {
            const uint4 z = {0, 0, 0, 0};
#pragma unroll
            for (int j = 0; j < K / 8; j += 8) *(uint4*)(dstp + j) = z;
        }
        if constexpr (POOL) {
            if (t < 32) s_batch[t] = (row0 + t < M) ? batch[row0 + t] : -1;
        }
    }
    __syncthreads();

    const int wv = t >> 6;
    const int lane = t & 63;
    const int m16 = lane & 15;
    const int quad = lane >> 4;

    floatx4 acc[2][4];
#pragma unroll
    for (int h2 = 0; h2 < 2; ++h2)
#pragma unroll
        for (int j = 0; j < 4; ++j) acc[h2][j] = (floatx4){0.f, 0.f, 0.f, 0.f};

    const unsigned short* ap0 = &sA[m16 * LDA + quad * 8];
    const unsigned short* ap1 = &sA[(16 + m16) * LDA + quad * 8];
    const unsigned short* bp = Wt + (size_t)(wv * 64 + m16) * K + quad * 8;

#pragma unroll
    for (int k0 = 0; k0 < K; k0 += 32) {
        const short8 a0 = *(const short8*)(ap0 + k0);
        const short8 a1 = *(const short8*)(ap1 + k0);
        const short8 b0 = *(const short8*)(bp + 0 * 16 * K + k0);
        const short8 b1 = *(const short8*)(bp + 1 * 16 * K + k0);
        const short8 b2 = *(const short8*)(bp + 2 * 16 * K + k0);
        const short8 b3 = *(const short8*)(bp + 3 * 16 * K + k0);
        acc[0][0] = __builtin_amdgcn_mfma_f32_16x16x32_bf16(a0, b0, acc[0][0], 0, 0, 0);
        acc[0][1] = __builtin_amdgcn_mfma_f32_16x16x32_bf16(a0, b1, acc[0][1], 0, 0, 0);
        acc[0][2] = __builtin_amdgcn_mfma_f32_16x16x32_bf16(a0, b2, acc[0][2], 0, 0, 0);
        acc[0][3] = __builtin_amdgcn_mfma_f32_16x16x32_bf16(a0, b3, acc[0][3], 0, 0, 0);
        acc[1][0] = __builtin_amdgcn_mfma_f32_16x16x32_bf16(a1, b0, acc[1][0], 0, 0, 0);
        acc[1][1] = __builtin_amdgcn_mfma_f32_16x16x32_bf16(a1, b1, acc[1][1], 0, 0, 0);
        acc[1][2] = __builtin_amdgcn_mfma_f32_16x16x32_bf16(a1, b2, acc[1][2], 0, 0, 0);
        acc[1][3] = __builtin_amdgcn_mfma_f32_16x16x32_bf16(a1, b3, acc[1][3], 0, 0, 0);
    }

    // D layout: col = lane&15 (N), row = quad*4 + reg (M within subtile)
    const int nbase = wv * 64 + m16;
    const float bb0 = bias[nbase + 0];
    const float bb1 = bias[nbase + 16];
    const float bb2 = bias[nbase + 32];
    const float bb3 = bias[nbase + 48];

    if constexpr (POOL) {
        // segment-sum relu'd rows over (sorted) batch ids, then atomic flush per segment
        float ps0 = 0.f, ps1 = 0.f, ps2 = 0.f, ps3 = 0.f;
        int gcur = -1;
#pragma unroll
        for (int h2 = 0; h2 < 2; ++h2) {
#pragma unroll
            for (int j = 0; j < 4; ++j) {
                const int rl = h2 * 16 + quad * 4 + j;
                const int g = s_batch[rl];
                if (g < 0) continue;       // padded row
                if (g != gcur) {
                    if (gcur >= 0) {
                        float* pp = pooled_sum + gcur * HID + nbase;
                        atomicAdd(pp + 0, ps0);
                        atomicAdd(pp + 16, ps1);
                        atomicAdd(pp + 32, ps2);
                        atomicAdd(pp + 48, ps3);
                    }
                    ps0 = ps1 = ps2 = ps3 = 0.f;
                    gcur = g;
                }
                ps0 += fmaxf(acc[h2][0][j] + bb0, 0.f);
                ps1 += fmaxf(acc[h2][1][j] + bb1, 0.f);
                ps2 += fmaxf(acc[h2][2][j] + bb2, 0.f);
                ps3 += fmaxf(acc[h2][3][j] + bb3, 0.f);
            }
        }
        if (gcur >= 0) {
            float* pp = pooled_sum + gcur * HID + nbase;
            atomicAdd(pp + 0, ps0);
            atomicAdd(pp + 16, ps1);
            atomicAdd(pp + 32, ps2);
            atomicAdd(pp + 48, ps3);
        }
    } else {
#pragma unroll
        for (int h2 = 0; h2 < 2; ++h2) {
#pragma unroll
            for (int j = 0; j < 4; ++j) {
                const int row = row0 + h2 * 16 + quad * 4 + j;
                if (row >= M) continue;
                float v0 = acc[h2][0][j] + bb0;
                float v1 = acc[h2][1][j] + bb1;
                float v2 = acc[h2][2][j] + bb2;
                float v3 = acc[h2][3][j] + bb3;
                if constexpr (RELU) {
                    v0 = fmaxf(v0, 0.f); v1 = fmaxf(v1, 0.f);
                    v2 = fmaxf(v2, 0.f); v3 = fmaxf(v3, 0.f);
                }
                if constexpr (sizeof(OT) == 4) {
                    out[(size_t)row * HID + nbase + 0]  = v0;
                    out[(size_t)row * HID + nbase + 16] = v1;
                    out[(size_t)row * HID + nbase + 32] = v2;
                    out[(size_t)row * HID + nbase + 48] = v3;
                } else {
                    out[(size_t)row * HID + nbase + 0]  = f2bf(v0);
                    out[(size_t)row * HID + nbase + 16] = f2bf(v1);
                    out[(size_t)row * HID + nbase + 32] = f2bf(v2);
                    out[(size_t)row * HID + nbase + 48] = f2bf(v3);
                }
            }
        }
    }
}

// ---------------- final FC with fused mean: out[g] = (sum[g] @ Wfc)/cnt + bfc ----------------
__global__ void k_fc(const float* __restrict__ pooled_sum, const int* __restrict__ batch,
                     const float* __restrict__ W, const float* __restrict__ b,
                     float* __restrict__ out, int n) {
    const int g = blockIdx.x;
    const int c = threadIdx.x;  // 128
    int a = 0, hi = n;
    while (a < hi) { int m = (a + hi) >> 1; if (batch[m] < g) a = m + 1; else hi = m; }
    const int start = a;
    hi = n;
    while (a < hi) { int m = (a + hi) >> 1; if (batch[m] < g + 1) a = m + 1; else hi = m; }
    const float cnt = (float)(a - start);

    float acc = 0.0f;
    const float* p = pooled_sum + g * HID;
    for (int k = 0; k < HID; ++k) acc += p[k] * W[k * OUTC + c];
    out[g * OUTC + c] = acc / fmaxf(cnt, 1.0f) + b[c];
}

extern "C" void kernel_launch(void* const* d_in, const int* in_sizes, int n_in,
                              void* d_out, int out_size, void* d_ws, size_t ws_size,
                              hipStream_t stream) {
    const float* x   = (const float*)d_in[0];
    const int*   ei  = (const int*)d_in[1];
    const int*   bat = (const int*)d_in[2];
    const float* W1  = (const float*)d_in[3];
    const float* b1  = (const float*)d_in[4];
    const float* W2  = (const float*)d_in[5];
    const float* b2  = (const float*)d_in[6];
    const float* Wfc = (const float*)d_in[7];
    const float* bfc = (const float*)d_in[8];
    float* out = (float*)d_out;

    const int n = in_sizes[2];       // 50000 nodes
    const int e = in_sizes[1] / 2;   // 800000 edges
    const int* src = ei;
    const int* dst = ei + e;
    const int nb = (n + 255) / 256;  // scan blocks (196 <= 256)

    // Workspace layout (each buffer 256B-aligned)
    size_t off = 0;
    auto alloc = [&](size_t bytes) {
        char* p = (char*)d_ws + off;
        off += (bytes + 255) & ~(size_t)255;
        return p;
    };
    int*   cnt     = (int*)alloc((size_t)n * 4);
    int*   row_ptr = (int*)alloc((size_t)(n + 1) * 4);
    int*   blk_sum = (int*)alloc(512 * 4);
    int*   csr_src = (int*)alloc((size_t)e * 4);
    float* dinv    = (float*)alloc((size_t)n * 4);
    unsigned short* Wt1 = (unsigned short*)alloc((size_t)INC * HID * 2);
    unsigned short* Wt2 = (unsigned short*)alloc((size_t)HID * HID * 2);
    unsigned short* R1  = (unsigned short*)alloc((size_t)n * HID * 2);  // xbf, later agg1
    unsigned short* R2  = (unsigned short*)alloc((size_t)n * INC * 2);  // agg0
    unsigned short* R3  = (unsigned short*)alloc((size_t)n * HID * 2);  // h1
    float* pooled = (float*)alloc((size_t)128 * HID * 4);               // fp32 sums

    const int TB = 256;
    hipMemsetAsync(cnt, 0, (size_t)n * 4, stream);
    hipMemsetAsync(pooled, 0, (size_t)128 * HID * 4, stream);

    // x -> bf16
    k_convX<<<((n * INC / 4) + TB - 1) / TB, TB, 0, stream>>>(x, R1, n * INC / 4);

    // CSR build (dinv fused into scan_local; blk-scan fused into scan_add)
    k_hist<<<(e + TB - 1) / TB, TB, 0, stream>>>(dst, cnt, e);
    k_scan_local<<<nb, TB, 0, stream>>>(cnt, row_ptr, blk_sum, dinv, n);
    k_scan_add<<<nb, TB, 0, stream>>>(row_ptr, blk_sum, cnt, n, e);
    k_fill<<<(e + TB - 1) / TB, TB, 0, stream>>>(src, dst, row_ptr, cnt, csr_src, e);

    // Both weight transposes in one dispatch
    k_convW<<<(INC * HID + HID * HID + TB - 1) / TB, TB, 0, stream>>>(W1, Wt1, W2, Wt2);

    const int gemm_blocks = (n + 31) / 32;
    const int agg_blocks = (n + 3) / 4;

    // Layer 1 (reordered via linearity): agg0 = A.x ; h1 = relu(agg0 @ W1 + b1)
    k_agg<INC><<<agg_blocks, TB, 0, stream>>>(R1, row_ptr, csr_src, dinv, R2, n);
    k_gemm_mfma<INC, true, false, unsigned short><<<gemm_blocks, TB, 0, stream>>>(
        R2, Wt1, b1, R3, nullptr, nullptr, n);

    // Layer 2: agg1 = A.h1 ; fused conv2 + relu + mean-pool partial sums (no out2 buffer)
    k_agg<HID><<<agg_blocks, TB, 0, stream>>>(R3, row_ptr, csr_src, dinv, R1, n);
    k_gemm_mfma<HID, true, true, float><<<gemm_blocks, TB, 0, stream>>>(
        R1, Wt2, b2, (float*)nullptr, bat, pooled, n);

    // FC with fused mean
    k_fc<<<128, 128, 0, stream>>>(pooled, bat, Wfc, bfc, out, n);
}